// Round 3
// baseline (1149.098 us; speedup 1.0000x reference)
//
#include <hip/hip_runtime.h>

#define N_NODES 100000
#define N_EDGES 3200000
#define D 16
#define L 3

#define TILE 64                    // dst nodes per bucket
#define NB ((N_NODES + TILE - 1) / TILE)   // 1563 buckets
#define NG 8                       // XCD groups (blockIdx % 8 heuristic)
#define NBLK 256                   // blocks for binning passes
#define SEG ((N_EDGES + NBLK - 1) / NBLK)  // 12500 edges per block segment

// ---- pass A: per-(bucket,group) histogram via LDS, one global atomic per (block,bucket) ----
__global__ void bin_hist(const int* __restrict__ dst, int* __restrict__ hist, int E) {
    __shared__ int lh[NB];
    for (int i = threadIdx.x; i < NB; i += 256) lh[i] = 0;
    __syncthreads();
    int b0 = blockIdx.x * SEG, b1 = min(E, b0 + SEG);
    for (int e = b0 + threadIdx.x; e < b1; e += 256)
        atomicAdd(&lh[dst[e] >> 6], 1);
    __syncthreads();
    int g = blockIdx.x & (NG - 1);
    for (int i = threadIdx.x; i < NB; i += 256) {
        int v = lh[i];
        if (v) atomicAdd(&hist[i * NG + g], v);
    }
}

// ---- exclusive scan of hist[NB*NG] -> start (kept) and cursor (mutated by scatter) ----
__global__ void scan_kernel(const int* __restrict__ hist, int* __restrict__ start,
                            int* __restrict__ cursor, int n) {
    __shared__ int s[256];
    int tid = threadIdx.x;
    int per = (n + 255) / 256;
    int lo = tid * per;
    int sum = 0;
    for (int i = 0; i < per; i++) { int idx = lo + i; if (idx < n) sum += hist[idx]; }
    s[tid] = sum; __syncthreads();
    for (int off = 1; off < 256; off <<= 1) {
        int t = (tid >= off) ? s[tid - off] : 0;
        __syncthreads();
        s[tid] += t;
        __syncthreads();
    }
    int acc = s[tid] - sum;  // exclusive prefix of this thread's chunk
    for (int i = 0; i < per; i++) {
        int idx = lo + i;
        if (idx < n) { int v = hist[idx]; start[idx] = acc; cursor[idx] = acc; acc += v; }
    }
}

// ---- pass B: scatter edges into bucket regions; per-edge atomics stay in LDS ----
// packed entry: (dst & 63) << 17 | src   (src < 2^17)
__global__ void bin_scatter(const int* __restrict__ src, const int* __restrict__ dst,
                            int* __restrict__ cursor, unsigned* __restrict__ ebuf, int E) {
    __shared__ int lcnt[NB];
    __shared__ int lbase[NB];
    for (int i = threadIdx.x; i < NB; i += 256) lcnt[i] = 0;
    __syncthreads();
    int b0 = blockIdx.x * SEG, b1 = min(E, b0 + SEG);
    for (int e = b0 + threadIdx.x; e < b1; e += 256)
        atomicAdd(&lcnt[dst[e] >> 6], 1);
    __syncthreads();
    int g = blockIdx.x & (NG - 1);
    for (int i = threadIdx.x; i < NB; i += 256) {
        int v = lcnt[i];
        lbase[i] = v ? atomicAdd(&cursor[i * NG + g], v) : 0;
    }
    __syncthreads();
    for (int i = threadIdx.x; i < NB; i += 256) lcnt[i] = 0;  // reuse as local cursor
    __syncthreads();
    for (int e = b0 + threadIdx.x; e < b1; e += 256) {
        int d = dst[e];
        int b_ = d >> 6;
        int pos = lbase[b_] + atomicAdd(&lcnt[b_], 1);
        ebuf[pos] = ((unsigned)(d & 63) << 17) | (unsigned)src[e];
    }
}

// ---- fused per-bucket aggregation (LDS atomics) + transform ----
// block = 256 threads, one bucket of 64 dst nodes. 4 lanes per edge for gather/accumulate,
// 4 lanes per node for the 16x16 transforms.
__global__ void agg_transform_kernel(const float* __restrict__ xin,
                                     const unsigned* __restrict__ ebuf,
                                     const int* __restrict__ start,
                                     const float* __restrict__ Wl,
                                     const float* __restrict__ bl,
                                     const float* __restrict__ Wr,
                                     const float* __restrict__ Wlin,
                                     const float* __restrict__ blin,
                                     float* __restrict__ xout, int N, int E) {
    __shared__ float sAgg[TILE * 17];   // 16 feats + deg, stride 17 (odd -> bank spread)
    __shared__ float sWl[D * D];
    __shared__ float sWc[D * D];
    __shared__ float sbc[D];

    int tid = threadIdx.x;
    if (tid < D * D) {
        sWl[tid] = Wl[tid];
        sWc[tid] = Wr[tid] + Wlin[tid];
    }
    if (tid < D) sbc[tid] = bl[tid] + blin[tid];
    for (int i = tid; i < TILE * 17; i += 256) sAgg[i] = 0.0f;
    __syncthreads();

    int b = blockIdx.x;
    int base = start[b * NG];
    int end = (b == NB - 1) ? E : start[(b + 1) * NG];
    int nE = end - base;
    int q = tid & 3;

    for (int i = (tid >> 2); i < nE; i += 64) {
        unsigned p = ebuf[base + i];
        int sloc = p >> 17;
        int s = p & 0x1FFFF;
        float4 v = *(const float4*)(xin + (size_t)s * D + q * 4);
        float* dp = &sAgg[sloc * 17 + q * 4];
        atomicAdd(dp + 0, v.x);
        atomicAdd(dp + 1, v.y);
        atomicAdd(dp + 2, v.z);
        atomicAdd(dp + 3, v.w);
        if (q == 0) atomicAdd(&sAgg[sloc * 17 + 16], 1.0f);
    }
    __syncthreads();

    int n_loc = tid >> 2;
    int n = b * TILE + n_loc;
    if (n >= N) return;

    float deg = sAgg[n_loc * 17 + 16];
    float inv = 1.0f / fmaxf(deg, 1.0f);
    float a[4], xv[4];
    #pragma unroll
    for (int k = 0; k < 4; k++) a[k] = sAgg[n_loc * 17 + q * 4 + k] * inv;
    float4 xq = *(const float4*)(xin + (size_t)n * D + q * 4);
    xv[0] = xq.x; xv[1] = xq.y; xv[2] = xq.z; xv[3] = xq.w;

    float o[4];
    #pragma unroll
    for (int j = 0; j < D; j++) {
        float p = 0.f;
        #pragma unroll
        for (int k = 0; k < 4; k++) {
            int kk = q * 4 + k;
            p += a[k] * sWl[j * D + kk] + xv[k] * sWc[j * D + kk];
        }
        p += __shfl_xor(p, 1, 4);
        p += __shfl_xor(p, 2, 4);
        if ((j >> 2) == q) o[j & 3] = p + sbc[j];
    }
    *(float4*)(xout + (size_t)n * D + q * 4) = make_float4(o[0], o[1], o[2], o[3]);
}

extern "C" void kernel_launch(void* const* d_in, const int* in_sizes, int n_in,
                              void* d_out, int out_size, void* d_ws, size_t ws_size,
                              hipStream_t stream) {
    const float* x    = (const float*)d_in[0];
    const int*   ei   = (const int*)d_in[1];   // (2, E): first E = src, next E = dst
    const float* Wl   = (const float*)d_in[2];
    const float* bl   = (const float*)d_in[3];
    const float* Wr   = (const float*)d_in[4];
    const float* Wlin = (const float*)d_in[5];
    const float* blin = (const float*)d_in[6];
    float* out = (float*)d_out;

    const int* src = ei;
    const int* dst = ei + N_EDGES;

    char* w = (char*)d_ws;
    unsigned* ebuf  = (unsigned*)w;  w += (size_t)N_EDGES * 4;       // 12.8 MB
    float* bufA     = (float*)w;     w += (size_t)N_NODES * D * 4;   // 6.4 MB
    float* bufB     = (float*)w;     w += (size_t)N_NODES * D * 4;   // 6.4 MB
    int*   hist     = (int*)w;       w += (size_t)NB * NG * 4;
    int*   startArr = (int*)w;       w += (size_t)NB * NG * 4;
    int*   cursor   = (int*)w;       w += (size_t)NB * NG * 4;

    hipMemsetAsync(hist, 0, (size_t)NB * NG * 4, stream);
    bin_hist<<<NBLK, 256, 0, stream>>>(dst, hist, N_EDGES);
    scan_kernel<<<1, 256, 0, stream>>>(hist, startArr, cursor, NB * NG);
    bin_scatter<<<NBLK, 256, 0, stream>>>(src, dst, cursor, ebuf, N_EDGES);

    const float* cur = x;
    float* nxts[L] = { bufA, bufB, out };
    for (int i = 0; i < L; i++) {
        agg_transform_kernel<<<NB, 256, 0, stream>>>(
            cur, ebuf, startArr,
            Wl + i * D * D, bl + i * D, Wr + i * D * D, Wlin + i * D * D, blin + i * D,
            nxts[i], N_NODES, N_EDGES);
        cur = nxts[i];
    }
}

// Round 4
// 341.363 us; speedup vs baseline: 3.3662x; 3.3662x over previous
//
#include <hip/hip_runtime.h>

#define N_NODES 100000
#define N_EDGES 3200000
#define D 16
#define L 3

#define TILE 64                            // dst nodes per bucket
#define NB ((N_NODES + TILE - 1) / TILE)   // 1563 buckets
#define NG 8                               // sub-cursors per bucket
#define NBLK 256                           // blocks for binning passes
#define SEG ((N_EDGES + NBLK - 1) / NBLK)  // edges per block segment
#define SORT_CAP 4096                      // LDS sort buffer (avg bucket = 2048, 45-sigma headroom)

// ---- pass A: per-(bucket,group) histogram via LDS, one global atomic per (block,bucket) ----
__global__ void bin_hist(const int* __restrict__ dst, int* __restrict__ hist, int E) {
    __shared__ int lh[NB];
    for (int i = threadIdx.x; i < NB; i += 256) lh[i] = 0;
    __syncthreads();
    int b0 = blockIdx.x * SEG, b1 = min(E, b0 + SEG);
    for (int e = b0 + threadIdx.x; e < b1; e += 256)
        atomicAdd(&lh[dst[e] >> 6], 1);
    __syncthreads();
    int g = blockIdx.x & (NG - 1);
    for (int i = threadIdx.x; i < NB; i += 256) {
        int v = lh[i];
        if (v) atomicAdd(&hist[i * NG + g], v);
    }
}

// ---- exclusive scan of hist[NB*NG] -> start, cursor ----
__global__ void scan_kernel(const int* __restrict__ hist, int* __restrict__ start,
                            int* __restrict__ cursor, int n) {
    __shared__ int s[256];
    int tid = threadIdx.x;
    int per = (n + 255) / 256;
    int lo = tid * per;
    int sum = 0;
    for (int i = 0; i < per; i++) { int idx = lo + i; if (idx < n) sum += hist[idx]; }
    s[tid] = sum; __syncthreads();
    for (int off = 1; off < 256; off <<= 1) {
        int t = (tid >= off) ? s[tid - off] : 0;
        __syncthreads();
        s[tid] += t;
        __syncthreads();
    }
    int acc = s[tid] - sum;
    for (int i = 0; i < per; i++) {
        int idx = lo + i;
        if (idx < n) { int v = hist[idx]; start[idx] = acc; cursor[idx] = acc; acc += v; }
    }
}

// ---- pass B: scatter edges into bucket regions; per-edge atomics stay in LDS ----
// packed entry: (dst & 63) << 17 | src   (src < 2^17)
__global__ void bin_scatter(const int* __restrict__ src, const int* __restrict__ dst,
                            int* __restrict__ cursor, unsigned* __restrict__ ebuf, int E) {
    __shared__ int lcnt[NB];
    __shared__ int lbase[NB];
    for (int i = threadIdx.x; i < NB; i += 256) lcnt[i] = 0;
    __syncthreads();
    int b0 = blockIdx.x * SEG, b1 = min(E, b0 + SEG);
    for (int e = b0 + threadIdx.x; e < b1; e += 256)
        atomicAdd(&lcnt[dst[e] >> 6], 1);
    __syncthreads();
    int g = blockIdx.x & (NG - 1);
    for (int i = threadIdx.x; i < NB; i += 256) {
        int v = lcnt[i];
        lbase[i] = v ? atomicAdd(&cursor[i * NG + g], v) : 0;
    }
    __syncthreads();
    for (int i = threadIdx.x; i < NB; i += 256) lcnt[i] = 0;  // reuse as local cursor
    __syncthreads();
    for (int e = b0 + threadIdx.x; e < b1; e += 256) {
        int d = dst[e];
        int b_ = d >> 6;
        int pos = lbase[b_] + atomicAdd(&lcnt[b_], 1);
        ebuf[pos] = ((unsigned)(d & 63) << 17) | (unsigned)src[e];
    }
}

// ---- pass C: per-bucket LDS counting sort (in place) -> full dst-sorted CSR + node_start ----
__global__ void sort_bucket(unsigned* __restrict__ ebuf, const int* __restrict__ start,
                            int* __restrict__ node_start, int E) {
    __shared__ unsigned se[SORT_CAP];
    __shared__ int lcnt[TILE];
    __shared__ int lofs[TILE];
    int tid = threadIdx.x;
    int b = blockIdx.x;
    int base = start[b * NG];
    int end = (b == NB - 1) ? E : start[(b + 1) * NG];
    int nE = end - base;
    if (tid < TILE) lcnt[tid] = 0;
    __syncthreads();
    for (int i = tid; i < nE; i += 256) {
        unsigned p = ebuf[base + i];
        se[i] = p;
        atomicAdd(&lcnt[p >> 17], 1);
    }
    __syncthreads();
    if (tid < TILE) {           // wave 0: inclusive shfl scan over 64 counters
        int v = lcnt[tid];
        int s = v;
        #pragma unroll
        for (int d_ = 1; d_ < TILE; d_ <<= 1) {
            int t = __shfl_up(s, d_, TILE);
            if (tid >= d_) s += t;
        }
        int excl = s - v;
        lofs[tid] = excl;
        node_start[b * TILE + tid] = base + excl;
        if (tid == TILE - 1 && b == NB - 1) node_start[b * TILE + TILE] = base + s;  // == E
    }
    __syncthreads();
    for (int i = tid; i < nE; i += 256) {
        unsigned p = se[i];
        int pos = atomicAdd(&lofs[p >> 17], 1);
        ebuf[base + pos] = p;
    }
}

// ---- fused per-layer: CSR mean-aggregate (4 lanes/node, unroll-4 gathers) + transform ----
__global__ void agg_transform_kernel(const float* __restrict__ xin,
                                     const unsigned* __restrict__ ebuf,
                                     const int* __restrict__ node_start,
                                     const float* __restrict__ Wl,
                                     const float* __restrict__ bl,
                                     const float* __restrict__ Wr,
                                     const float* __restrict__ Wlin,
                                     const float* __restrict__ blin,
                                     float* __restrict__ xout, int N) {
    __shared__ float sWl[D * D];
    __shared__ float sWc[D * D];
    __shared__ float sbc[D];
    int tid = threadIdx.x;
    if (tid < D * D) {
        sWl[tid] = Wl[tid];
        sWc[tid] = Wr[tid] + Wlin[tid];
    }
    if (tid < D) sbc[tid] = bl[tid] + blin[tid];
    __syncthreads();

    int t = blockIdx.x * blockDim.x + tid;
    int n = t >> 2;
    int q = t & 3;
    if (n >= N) return;

    int s0 = node_start[n];
    int s1 = node_start[n + 1];
    int deg = s1 - s0;

    float4 acc = make_float4(0.f, 0.f, 0.f, 0.f);
    int i = s0;
    for (; i + 4 <= s1; i += 4) {               // 4 independent gathers in flight
        unsigned p0 = ebuf[i] & 0x1FFFF;
        unsigned p1 = ebuf[i + 1] & 0x1FFFF;
        unsigned p2 = ebuf[i + 2] & 0x1FFFF;
        unsigned p3 = ebuf[i + 3] & 0x1FFFF;
        float4 v0 = *(const float4*)(xin + (size_t)p0 * D + q * 4);
        float4 v1 = *(const float4*)(xin + (size_t)p1 * D + q * 4);
        float4 v2 = *(const float4*)(xin + (size_t)p2 * D + q * 4);
        float4 v3 = *(const float4*)(xin + (size_t)p3 * D + q * 4);
        acc.x += v0.x + v1.x + v2.x + v3.x;
        acc.y += v0.y + v1.y + v2.y + v3.y;
        acc.z += v0.z + v1.z + v2.z + v3.z;
        acc.w += v0.w + v1.w + v2.w + v3.w;
    }
    for (; i < s1; i++) {
        unsigned p = ebuf[i] & 0x1FFFF;
        float4 v = *(const float4*)(xin + (size_t)p * D + q * 4);
        acc.x += v.x; acc.y += v.y; acc.z += v.z; acc.w += v.w;
    }

    float inv = 1.0f / fmaxf((float)deg, 1.0f);
    float a[4] = { acc.x * inv, acc.y * inv, acc.z * inv, acc.w * inv };
    float4 xq = *(const float4*)(xin + (size_t)n * D + q * 4);
    float xv[4] = { xq.x, xq.y, xq.z, xq.w };

    float o[4];
    #pragma unroll
    for (int j = 0; j < D; j++) {
        float p = 0.f;
        #pragma unroll
        for (int k = 0; k < 4; k++) {
            int kk = q * 4 + k;
            p += a[k] * sWl[j * D + kk] + xv[k] * sWc[j * D + kk];
        }
        p += __shfl_xor(p, 1, 4);
        p += __shfl_xor(p, 2, 4);
        if ((j >> 2) == q) o[j & 3] = p + sbc[j];
    }
    *(float4*)(xout + (size_t)n * D + q * 4) = make_float4(o[0], o[1], o[2], o[3]);
}

extern "C" void kernel_launch(void* const* d_in, const int* in_sizes, int n_in,
                              void* d_out, int out_size, void* d_ws, size_t ws_size,
                              hipStream_t stream) {
    const float* x    = (const float*)d_in[0];
    const int*   ei   = (const int*)d_in[1];   // (2, E): first E = src, next E = dst
    const float* Wl   = (const float*)d_in[2];
    const float* bl   = (const float*)d_in[3];
    const float* Wr   = (const float*)d_in[4];
    const float* Wlin = (const float*)d_in[5];
    const float* blin = (const float*)d_in[6];
    float* out = (float*)d_out;

    const int* src = ei;
    const int* dst = ei + N_EDGES;

    char* w = (char*)d_ws;
    unsigned* ebuf   = (unsigned*)w;  w += (size_t)N_EDGES * 4;        // 12.8 MB
    float* bufA      = (float*)w;     w += (size_t)N_NODES * D * 4;    // 6.4 MB
    float* bufB      = (float*)w;     w += (size_t)N_NODES * D * 4;    // 6.4 MB
    int*   hist      = (int*)w;       w += (size_t)NB * NG * 4;
    int*   startArr  = (int*)w;       w += (size_t)NB * NG * 4;
    int*   cursor    = (int*)w;       w += (size_t)NB * NG * 4;
    int*   node_start= (int*)w;       w += ((size_t)NB * TILE + 1) * 4; // 400 KB

    hipMemsetAsync(hist, 0, (size_t)NB * NG * 4, stream);
    bin_hist<<<NBLK, 256, 0, stream>>>(dst, hist, N_EDGES);
    scan_kernel<<<1, 256, 0, stream>>>(hist, startArr, cursor, NB * NG);
    bin_scatter<<<NBLK, 256, 0, stream>>>(src, dst, cursor, ebuf, N_EDGES);
    sort_bucket<<<NB, 256, 0, stream>>>(ebuf, startArr, node_start, N_EDGES);

    const float* cur = x;
    float* nxts[L] = { bufA, bufB, out };
    for (int i = 0; i < L; i++) {
        agg_transform_kernel<<<((N_NODES * 4) + 255) / 256, 256, 0, stream>>>(
            cur, ebuf, node_start,
            Wl + i * D * D, bl + i * D, Wr + i * D * D, Wlin + i * D * D, blin + i * D,
            nxts[i], N_NODES);
        cur = nxts[i];
    }
}

// Round 5
// 303.110 us; speedup vs baseline: 3.7910x; 1.1262x over previous
//
#include <hip/hip_runtime.h>

#define N_NODES 100000
#define N_EDGES 3200000
#define D 16
#define L 3

#define TILE 64                            // dst nodes per bucket
#define NB ((N_NODES + TILE - 1) / TILE)   // 1563 buckets
#define NG 8                               // sub-cursors per bucket
#define NBLK 256                           // blocks for binning passes
#define SEG ((N_EDGES + NBLK - 1) / NBLK)  // edges per block segment
#define BINT 1024                          // threads for binning passes
#define SORT_CAP 4096                      // LDS sort buffer (avg bucket = 2048)
#define SORT_T 512                         // threads for sort pass

// ---- pass A: per-(bucket,group) histogram via LDS, one global atomic per (block,bucket) ----
__global__ void bin_hist(const int* __restrict__ dst, int* __restrict__ hist, int E) {
    __shared__ int lh[NB];
    for (int i = threadIdx.x; i < NB; i += BINT) lh[i] = 0;
    __syncthreads();
    int b0 = blockIdx.x * SEG, b1 = min(E, b0 + SEG);
    for (int e = b0 + threadIdx.x; e < b1; e += BINT)
        atomicAdd(&lh[dst[e] >> 6], 1);
    __syncthreads();
    int g = blockIdx.x & (NG - 1);
    for (int i = threadIdx.x; i < NB; i += BINT) {
        int v = lh[i];
        if (v) atomicAdd(&hist[i * NG + g], v);
    }
}

// ---- exclusive scan of hist[NB*NG] -> start, cursor ----
__global__ void scan_kernel(const int* __restrict__ hist, int* __restrict__ start,
                            int* __restrict__ cursor, int n) {
    __shared__ int s[256];
    int tid = threadIdx.x;
    int per = (n + 255) / 256;
    int lo = tid * per;
    int sum = 0;
    for (int i = 0; i < per; i++) { int idx = lo + i; if (idx < n) sum += hist[idx]; }
    s[tid] = sum; __syncthreads();
    for (int off = 1; off < 256; off <<= 1) {
        int t = (tid >= off) ? s[tid - off] : 0;
        __syncthreads();
        s[tid] += t;
        __syncthreads();
    }
    int acc = s[tid] - sum;
    for (int i = 0; i < per; i++) {
        int idx = lo + i;
        if (idx < n) { int v = hist[idx]; start[idx] = acc; cursor[idx] = acc; acc += v; }
    }
}

// ---- pass B: scatter edges into bucket regions; per-edge atomics stay in LDS ----
// packed entry: (dst & 63) << 17 | src   (src < 2^17)
__global__ void bin_scatter(const int* __restrict__ src, const int* __restrict__ dst,
                            int* __restrict__ cursor, unsigned* __restrict__ ebuf, int E) {
    __shared__ int lcnt[NB];
    __shared__ int lbase[NB];
    for (int i = threadIdx.x; i < NB; i += BINT) lcnt[i] = 0;
    __syncthreads();
    int b0 = blockIdx.x * SEG, b1 = min(E, b0 + SEG);
    for (int e = b0 + threadIdx.x; e < b1; e += BINT)
        atomicAdd(&lcnt[dst[e] >> 6], 1);
    __syncthreads();
    int g = blockIdx.x & (NG - 1);
    for (int i = threadIdx.x; i < NB; i += BINT) {
        int v = lcnt[i];
        lbase[i] = v ? atomicAdd(&cursor[i * NG + g], v) : 0;
    }
    __syncthreads();
    for (int i = threadIdx.x; i < NB; i += BINT) lcnt[i] = 0;  // reuse as local cursor
    __syncthreads();
    for (int e = b0 + threadIdx.x; e < b1; e += BINT) {
        int d = dst[e];
        int b_ = d >> 6;
        int pos = lbase[b_] + atomicAdd(&lcnt[b_], 1);
        ebuf[pos] = ((unsigned)(d & 63) << 17) | (unsigned)src[e];
    }
}

// ---- pass C: per-bucket LDS counting sort (in place) -> full dst-sorted CSR + node_start ----
__global__ void sort_bucket(unsigned* __restrict__ ebuf, const int* __restrict__ start,
                            int* __restrict__ node_start, int E) {
    __shared__ unsigned se[SORT_CAP];
    __shared__ int lcnt[TILE];
    __shared__ int lofs[TILE];
    int tid = threadIdx.x;
    int b = blockIdx.x;
    int base = start[b * NG];
    int end = (b == NB - 1) ? E : start[(b + 1) * NG];
    int nE = end - base;
    if (tid < TILE) lcnt[tid] = 0;
    __syncthreads();
    for (int i = tid; i < nE; i += SORT_T) {
        unsigned p = ebuf[base + i];
        se[i] = p;
        atomicAdd(&lcnt[p >> 17], 1);
    }
    __syncthreads();
    if (tid < TILE) {           // wave 0: inclusive shfl scan over 64 counters
        int v = lcnt[tid];
        int s = v;
        #pragma unroll
        for (int d_ = 1; d_ < TILE; d_ <<= 1) {
            int t = __shfl_up(s, d_, TILE);
            if (tid >= d_) s += t;
        }
        int excl = s - v;
        lofs[tid] = excl;
        node_start[b * TILE + tid] = base + excl;
        if (tid == TILE - 1 && b == NB - 1) node_start[b * TILE + TILE] = base + s;  // == E
    }
    __syncthreads();
    for (int i = tid; i < nE; i += SORT_T) {
        unsigned p = se[i];
        int pos = atomicAdd(&lofs[p >> 17], 1);
        ebuf[base + pos] = p;
    }
}

// ---- fused per-layer: CSR mean-aggregate (4 lanes/node, unroll-8 gathers) + transform ----
__global__ void agg_transform_kernel(const float* __restrict__ xin,
                                     const unsigned* __restrict__ ebuf,
                                     const int* __restrict__ node_start,
                                     const float* __restrict__ Wl,
                                     const float* __restrict__ bl,
                                     const float* __restrict__ Wr,
                                     const float* __restrict__ Wlin,
                                     const float* __restrict__ blin,
                                     float* __restrict__ xout, int N) {
    __shared__ float sWl[D * D];
    __shared__ float sWc[D * D];
    __shared__ float sbc[D];
    int tid = threadIdx.x;
    if (tid < D * D) {
        sWl[tid] = Wl[tid];
        sWc[tid] = Wr[tid] + Wlin[tid];
    }
    if (tid < D) sbc[tid] = bl[tid] + blin[tid];
    __syncthreads();

    int t = blockIdx.x * blockDim.x + tid;
    int n = t >> 2;
    int q = t & 3;
    if (n >= N) return;

    int s0 = node_start[n];
    int s1 = node_start[n + 1];
    int deg = s1 - s0;

    float4 acc0 = make_float4(0.f, 0.f, 0.f, 0.f);
    float4 acc1 = make_float4(0.f, 0.f, 0.f, 0.f);
    int i = s0;
    for (; i + 8 <= s1; i += 8) {               // 8 independent gathers in flight
        unsigned p[8];
        #pragma unroll
        for (int j = 0; j < 8; j++) p[j] = ebuf[i + j] & 0x1FFFF;
        float4 v[8];
        #pragma unroll
        for (int j = 0; j < 8; j++) v[j] = *(const float4*)(xin + (size_t)p[j] * D + q * 4);
        #pragma unroll
        for (int j = 0; j < 8; j += 2) {
            acc0.x += v[j].x; acc0.y += v[j].y; acc0.z += v[j].z; acc0.w += v[j].w;
            acc1.x += v[j + 1].x; acc1.y += v[j + 1].y; acc1.z += v[j + 1].z; acc1.w += v[j + 1].w;
        }
    }
    for (; i < s1; i++) {
        unsigned p = ebuf[i] & 0x1FFFF;
        float4 v = *(const float4*)(xin + (size_t)p * D + q * 4);
        acc0.x += v.x; acc0.y += v.y; acc0.z += v.z; acc0.w += v.w;
    }
    float4 acc = make_float4(acc0.x + acc1.x, acc0.y + acc1.y,
                             acc0.z + acc1.z, acc0.w + acc1.w);

    float inv = 1.0f / fmaxf((float)deg, 1.0f);
    float a[4] = { acc.x * inv, acc.y * inv, acc.z * inv, acc.w * inv };
    float4 xq = *(const float4*)(xin + (size_t)n * D + q * 4);
    float xv[4] = { xq.x, xq.y, xq.z, xq.w };

    float o[4];
    #pragma unroll
    for (int j = 0; j < D; j++) {
        float p = 0.f;
        #pragma unroll
        for (int k = 0; k < 4; k++) {
            int kk = q * 4 + k;
            p += a[k] * sWl[j * D + kk] + xv[k] * sWc[j * D + kk];
        }
        p += __shfl_xor(p, 1, 4);
        p += __shfl_xor(p, 2, 4);
        if ((j >> 2) == q) o[j & 3] = p + sbc[j];
    }
    *(float4*)(xout + (size_t)n * D + q * 4) = make_float4(o[0], o[1], o[2], o[3]);
}

extern "C" void kernel_launch(void* const* d_in, const int* in_sizes, int n_in,
                              void* d_out, int out_size, void* d_ws, size_t ws_size,
                              hipStream_t stream) {
    const float* x    = (const float*)d_in[0];
    const int*   ei   = (const int*)d_in[1];   // (2, E): first E = src, next E = dst
    const float* Wl   = (const float*)d_in[2];
    const float* bl   = (const float*)d_in[3];
    const float* Wr   = (const float*)d_in[4];
    const float* Wlin = (const float*)d_in[5];
    const float* blin = (const float*)d_in[6];
    float* out = (float*)d_out;

    const int* src = ei;
    const int* dst = ei + N_EDGES;

    char* w = (char*)d_ws;
    unsigned* ebuf   = (unsigned*)w;  w += (size_t)N_EDGES * 4;        // 12.8 MB
    float* bufA      = (float*)w;     w += (size_t)N_NODES * D * 4;    // 6.4 MB
    float* bufB      = (float*)w;     w += (size_t)N_NODES * D * 4;    // 6.4 MB
    int*   hist      = (int*)w;       w += (size_t)NB * NG * 4;
    int*   startArr  = (int*)w;       w += (size_t)NB * NG * 4;
    int*   cursor    = (int*)w;       w += (size_t)NB * NG * 4;
    int*   node_start= (int*)w;       w += ((size_t)NB * TILE + 1) * 4; // 400 KB

    hipMemsetAsync(hist, 0, (size_t)NB * NG * 4, stream);
    bin_hist<<<NBLK, BINT, 0, stream>>>(dst, hist, N_EDGES);
    scan_kernel<<<1, 256, 0, stream>>>(hist, startArr, cursor, NB * NG);
    bin_scatter<<<NBLK, BINT, 0, stream>>>(src, dst, cursor, ebuf, N_EDGES);
    sort_bucket<<<NB, SORT_T, 0, stream>>>(ebuf, startArr, node_start, N_EDGES);

    const float* cur = x;
    float* nxts[L] = { bufA, bufB, out };
    for (int i = 0; i < L; i++) {
        agg_transform_kernel<<<((N_NODES * 4) + 255) / 256, 256, 0, stream>>>(
            cur, ebuf, node_start,
            Wl + i * D * D, bl + i * D, Wr + i * D * D, Wlin + i * D * D, blin + i * D,
            nxts[i], N_NODES);
        cur = nxts[i];
    }
}

// Round 6
// 293.944 us; speedup vs baseline: 3.9092x; 1.0312x over previous
//
#include <hip/hip_runtime.h>

#define N_NODES 100000
#define N_EDGES 3200000
#define D 16
#define L 3

#define TILE 64                            // dst nodes per bucket
#define NB ((N_NODES + TILE - 1) / TILE)   // 1563 buckets
#define NG 8                               // sub-cursors per bucket
#define NBLK 500                           // blocks for binning passes (~2/CU)
#define SEG (N_EDGES / NBLK)               // 6400 edges per block segment (%4==0)
#define BINT 1024                          // threads for binning passes
#define SORT_CAP 4096                      // LDS edge buffer (avg bucket = 2048, huge margin)

// ---- pass A: per-(bucket,group) histogram via LDS, one global atomic per (block,bucket) ----
__global__ void bin_hist(const int* __restrict__ dst, int* __restrict__ hist, int E) {
    __shared__ int lh[NB];
    for (int i = threadIdx.x; i < NB; i += BINT) lh[i] = 0;
    __syncthreads();
    int b0 = blockIdx.x * SEG, b1 = min(E, b0 + SEG);
    for (int e = b0 + threadIdx.x * 4; e < b1; e += BINT * 4) {
        int4 d4 = *(const int4*)(dst + e);
        atomicAdd(&lh[d4.x >> 6], 1);
        atomicAdd(&lh[d4.y >> 6], 1);
        atomicAdd(&lh[d4.z >> 6], 1);
        atomicAdd(&lh[d4.w >> 6], 1);
    }
    __syncthreads();
    int g = blockIdx.x & (NG - 1);
    for (int i = threadIdx.x; i < NB; i += BINT) {
        int v = lh[i];
        if (v) atomicAdd(&hist[i * NG + g], v);
    }
}

// ---- exclusive scan of hist[NB*NG] -> start, cursor ----
__global__ void scan_kernel(const int* __restrict__ hist, int* __restrict__ start,
                            int* __restrict__ cursor, int n) {
    __shared__ int s[256];
    int tid = threadIdx.x;
    int per = (n + 255) / 256;
    int lo = tid * per;
    int sum = 0;
    for (int i = 0; i < per; i++) { int idx = lo + i; if (idx < n) sum += hist[idx]; }
    s[tid] = sum; __syncthreads();
    for (int off = 1; off < 256; off <<= 1) {
        int t = (tid >= off) ? s[tid - off] : 0;
        __syncthreads();
        s[tid] += t;
        __syncthreads();
    }
    int acc = s[tid] - sum;
    for (int i = 0; i < per; i++) {
        int idx = lo + i;
        if (idx < n) { int v = hist[idx]; start[idx] = acc; cursor[idx] = acc; acc += v; }
    }
}

// ---- pass B: scatter edges into bucket regions; per-edge atomics stay in LDS ----
// packed entry: (dst & 63) << 17 | src   (src < 2^17)
__global__ void bin_scatter(const int* __restrict__ src, const int* __restrict__ dst,
                            int* __restrict__ cursor, unsigned* __restrict__ ebuf, int E) {
    __shared__ int lcnt[NB];
    __shared__ int lbase[NB];
    for (int i = threadIdx.x; i < NB; i += BINT) lcnt[i] = 0;
    __syncthreads();
    int b0 = blockIdx.x * SEG, b1 = min(E, b0 + SEG);
    for (int e = b0 + threadIdx.x * 4; e < b1; e += BINT * 4) {
        int4 d4 = *(const int4*)(dst + e);
        atomicAdd(&lcnt[d4.x >> 6], 1);
        atomicAdd(&lcnt[d4.y >> 6], 1);
        atomicAdd(&lcnt[d4.z >> 6], 1);
        atomicAdd(&lcnt[d4.w >> 6], 1);
    }
    __syncthreads();
    int g = blockIdx.x & (NG - 1);
    for (int i = threadIdx.x; i < NB; i += BINT) {
        int v = lcnt[i];
        lbase[i] = v ? atomicAdd(&cursor[i * NG + g], v) : 0;
    }
    __syncthreads();
    for (int i = threadIdx.x; i < NB; i += BINT) lcnt[i] = 0;  // reuse as local cursor
    __syncthreads();
    for (int e = b0 + threadIdx.x * 4; e < b1; e += BINT * 4) {
        int4 d4 = *(const int4*)(dst + e);
        int4 s4 = *(const int4*)(src + e);
        int b_, pos;
        b_ = d4.x >> 6; pos = lbase[b_] + atomicAdd(&lcnt[b_], 1);
        ebuf[pos] = ((unsigned)(d4.x & 63) << 17) | (unsigned)s4.x;
        b_ = d4.y >> 6; pos = lbase[b_] + atomicAdd(&lcnt[b_], 1);
        ebuf[pos] = ((unsigned)(d4.y & 63) << 17) | (unsigned)s4.y;
        b_ = d4.z >> 6; pos = lbase[b_] + atomicAdd(&lcnt[b_], 1);
        ebuf[pos] = ((unsigned)(d4.z & 63) << 17) | (unsigned)s4.z;
        b_ = d4.w >> 6; pos = lbase[b_] + atomicAdd(&lcnt[b_], 1);
        ebuf[pos] = ((unsigned)(d4.w & 63) << 17) | (unsigned)s4.w;
    }
}

// ---- fused per-layer kernel: one block per bucket ----
// layer 1 (do_sort=1): load bucket edges -> LDS counting sort -> coalesced write-back
//                      + node_start, then aggregate+transform from LDS.
// layers 2/3 (do_sort=0): coalesced load of sorted edges -> aggregate+transform.
__global__ void layer_kernel(const float* __restrict__ xin,
                             unsigned* __restrict__ ebuf,
                             const int* __restrict__ start,
                             int* __restrict__ node_start,
                             const float* __restrict__ Wl,
                             const float* __restrict__ bl,
                             const float* __restrict__ Wr,
                             const float* __restrict__ Wlin,
                             const float* __restrict__ blin,
                             float* __restrict__ xout, int N, int E, int do_sort) {
    __shared__ unsigned se[SORT_CAP];    // raw edges (sort scratch)
    __shared__ unsigned se2[SORT_CAP];   // sorted edges
    __shared__ int lcnt[TILE];
    __shared__ int lofs[TILE + 1];
    __shared__ float sWl[D * D];
    __shared__ float sWc[D * D];
    __shared__ float sbc[D];

    int tid = threadIdx.x;
    int b = blockIdx.x;
    int base = start[b * NG];
    int end = (b == NB - 1) ? E : start[(b + 1) * NG];
    int nE = min(end - base, SORT_CAP);

    if (tid < D * D) {
        sWl[tid] = Wl[tid];
        sWc[tid] = Wr[tid] + Wlin[tid];
    }
    if (tid < D) sbc[tid] = bl[tid] + blin[tid];

    if (do_sort) {
        if (tid < TILE) lcnt[tid] = 0;
        __syncthreads();
        for (int i = tid; i < nE; i += 256) {
            unsigned p = ebuf[base + i];
            se[i] = p;
            atomicAdd(&lcnt[p >> 17], 1);
        }
        __syncthreads();
        if (tid < TILE) {                // wave 0: inclusive shfl scan over 64 counters
            int v = lcnt[tid];
            int s = v;
            #pragma unroll
            for (int d_ = 1; d_ < TILE; d_ <<= 1) {
                int t = __shfl_up(s, d_, TILE);
                if (tid >= d_) s += t;
            }
            int excl = s - v;
            lofs[tid] = excl;
            lcnt[tid] = excl;            // running cursor for reorder
            node_start[b * TILE + tid] = base + excl;
            if (tid == TILE - 1) lofs[TILE] = s;  // == nE
        }
        __syncthreads();
        for (int i = tid; i < nE; i += 256) {
            unsigned p = se[i];
            int pos = atomicAdd(&lcnt[p >> 17], 1);
            se2[pos] = p;
        }
        __syncthreads();
        for (int i = tid; i < nE; i += 256)   // coalesced sorted write-back for layers 2/3
            ebuf[base + i] = se2[i];
    } else {
        if (tid < TILE) {
            lofs[tid] = node_start[b * TILE + tid] - base;
            if (tid == TILE - 1) lofs[TILE] = nE;
        }
        for (int i = tid; i < nE; i += 256) se2[i] = ebuf[base + i];
        __syncthreads();
    }

    // ---- aggregation + transform: 4 lanes per node ----
    int n_loc = tid >> 2;
    int q = tid & 3;
    int n = b * TILE + n_loc;
    if (n >= N) return;

    int s0 = lofs[n_loc];
    int s1 = lofs[n_loc + 1];
    int deg = s1 - s0;

    float4 acc0 = make_float4(0.f, 0.f, 0.f, 0.f);
    float4 acc1 = make_float4(0.f, 0.f, 0.f, 0.f);
    int i = s0;
    for (; i + 8 <= s1; i += 8) {               // 8 independent gathers in flight
        unsigned p[8];
        #pragma unroll
        for (int j = 0; j < 8; j++) p[j] = se2[i + j] & 0x1FFFF;
        float4 v[8];
        #pragma unroll
        for (int j = 0; j < 8; j++) v[j] = *(const float4*)(xin + (size_t)p[j] * D + q * 4);
        #pragma unroll
        for (int j = 0; j < 8; j += 2) {
            acc0.x += v[j].x; acc0.y += v[j].y; acc0.z += v[j].z; acc0.w += v[j].w;
            acc1.x += v[j + 1].x; acc1.y += v[j + 1].y; acc1.z += v[j + 1].z; acc1.w += v[j + 1].w;
        }
    }
    for (; i < s1; i++) {
        unsigned p = se2[i] & 0x1FFFF;
        float4 v = *(const float4*)(xin + (size_t)p * D + q * 4);
        acc0.x += v.x; acc0.y += v.y; acc0.z += v.z; acc0.w += v.w;
    }
    float4 acc = make_float4(acc0.x + acc1.x, acc0.y + acc1.y,
                             acc0.z + acc1.z, acc0.w + acc1.w);

    float inv = 1.0f / fmaxf((float)deg, 1.0f);
    float a[4] = { acc.x * inv, acc.y * inv, acc.z * inv, acc.w * inv };
    float4 xq = *(const float4*)(xin + (size_t)n * D + q * 4);
    float xv[4] = { xq.x, xq.y, xq.z, xq.w };

    float o[4];
    #pragma unroll
    for (int j = 0; j < D; j++) {
        float p = 0.f;
        #pragma unroll
        for (int k = 0; k < 4; k++) {
            int kk = q * 4 + k;
            p += a[k] * sWl[j * D + kk] + xv[k] * sWc[j * D + kk];
        }
        p += __shfl_xor(p, 1, 4);
        p += __shfl_xor(p, 2, 4);
        if ((j >> 2) == q) o[j & 3] = p + sbc[j];
    }
    *(float4*)(xout + (size_t)n * D + q * 4) = make_float4(o[0], o[1], o[2], o[3]);
}

extern "C" void kernel_launch(void* const* d_in, const int* in_sizes, int n_in,
                              void* d_out, int out_size, void* d_ws, size_t ws_size,
                              hipStream_t stream) {
    const float* x    = (const float*)d_in[0];
    const int*   ei   = (const int*)d_in[1];   // (2, E): first E = src, next E = dst
    const float* Wl   = (const float*)d_in[2];
    const float* bl   = (const float*)d_in[3];
    const float* Wr   = (const float*)d_in[4];
    const float* Wlin = (const float*)d_in[5];
    const float* blin = (const float*)d_in[6];
    float* out = (float*)d_out;

    const int* src = ei;
    const int* dst = ei + N_EDGES;

    char* w = (char*)d_ws;
    unsigned* ebuf   = (unsigned*)w;  w += (size_t)N_EDGES * 4;        // 12.8 MB
    float* bufA      = (float*)w;     w += (size_t)N_NODES * D * 4;    // 6.4 MB
    float* bufB      = (float*)w;     w += (size_t)N_NODES * D * 4;    // 6.4 MB
    int*   hist      = (int*)w;       w += (size_t)NB * NG * 4;
    int*   startArr  = (int*)w;       w += (size_t)NB * NG * 4;
    int*   cursor    = (int*)w;       w += (size_t)NB * NG * 4;
    int*   node_start= (int*)w;       w += ((size_t)NB * TILE + 1) * 4; // 400 KB

    hipMemsetAsync(hist, 0, (size_t)NB * NG * 4, stream);
    bin_hist<<<NBLK, BINT, 0, stream>>>(dst, hist, N_EDGES);
    scan_kernel<<<1, 256, 0, stream>>>(hist, startArr, cursor, NB * NG);
    bin_scatter<<<NBLK, BINT, 0, stream>>>(src, dst, cursor, ebuf, N_EDGES);

    const float* cur = x;
    float* nxts[L] = { bufA, bufB, out };
    for (int i = 0; i < L; i++) {
        layer_kernel<<<NB, 256, 0, stream>>>(
            cur, ebuf, startArr, node_start,
            Wl + i * D * D, bl + i * D, Wr + i * D * D, Wlin + i * D * D, blin + i * D,
            nxts[i], N_NODES, N_EDGES, i == 0 ? 1 : 0);
        cur = nxts[i];
    }
}

// Round 7
// 217.150 us; speedup vs baseline: 5.2917x; 1.3536x over previous
//
#include <hip/hip_runtime.h>

#define N_NODES 100000
#define N_EDGES 3200000
#define D 16
#define L 3

#define TILE 64                            // dst nodes per bucket
#define NB ((N_NODES + TILE - 1) / TILE)   // 1563 buckets
#define CAP 3072                           // fixed ebuf region per bucket (mean 2048, +22 sigma)
#define NBLK 500                           // blocks for scatter pass
#define SEG (N_EDGES / NBLK)               // 6400 edges per block (multiple of 4)
#define BINT 1024                          // threads for scatter pass

// ---- bf16 helpers (RNE) ----
__device__ __forceinline__ unsigned packbf(float a, float b) {
    unsigned ua = __float_as_uint(a); ua += 0x7FFFu + ((ua >> 16) & 1u);
    unsigned ub = __float_as_uint(b); ub += 0x7FFFu + ((ub >> 16) & 1u);
    return (ua >> 16) | (ub & 0xFFFF0000u);
}
#define BLO(u) __uint_as_float((u) << 16)
#define BHI(u) __uint_as_float((u) & 0xFFFF0000u)

// x (fp32) -> xbf mirror (bf16 rows of 32B); t indexes float4 quarters
__global__ void cvt_kernel(const float* __restrict__ x, unsigned* __restrict__ xbf, int n4) {
    int t = blockIdx.x * blockDim.x + threadIdx.x;
    if (t >= n4) return;
    float4 v = *(const float4*)(x + (size_t)t * 4);
    uint2 o; o.x = packbf(v.x, v.y); o.y = packbf(v.z, v.w);
    *(uint2*)(xbf + (size_t)t * 2) = o;
}

// ---- single-pass scatter: LDS per-block histogram, direct global reservation ----
// packed entry: (dst & 63) << 17 | src   (src < 2^17)
__global__ void bin_scatter(const int* __restrict__ src, const int* __restrict__ dst,
                            int* __restrict__ cursor, unsigned* __restrict__ ebuf, int E) {
    __shared__ int lcnt[NB];
    __shared__ int lbase[NB];
    for (int i = threadIdx.x; i < NB; i += BINT) lcnt[i] = 0;
    __syncthreads();
    int b0 = blockIdx.x * SEG, b1 = min(E, b0 + SEG);
    for (int e = b0 + threadIdx.x * 4; e < b1; e += BINT * 4) {
        int4 d4 = *(const int4*)(dst + e);
        atomicAdd(&lcnt[d4.x >> 6], 1);
        atomicAdd(&lcnt[d4.y >> 6], 1);
        atomicAdd(&lcnt[d4.z >> 6], 1);
        atomicAdd(&lcnt[d4.w >> 6], 1);
    }
    __syncthreads();
    for (int i = threadIdx.x; i < NB; i += BINT) {
        int v = lcnt[i];
        lbase[i] = v ? (i * CAP + atomicAdd(&cursor[i], v)) : 0;
    }
    __syncthreads();
    for (int i = threadIdx.x; i < NB; i += BINT) lcnt[i] = 0;  // reuse as local cursor
    __syncthreads();
    for (int e = b0 + threadIdx.x * 4; e < b1; e += BINT * 4) {
        int4 d4 = *(const int4*)(dst + e);
        int4 s4 = *(const int4*)(src + e);
        int b_, pos;
        b_ = d4.x >> 6; pos = lbase[b_] + atomicAdd(&lcnt[b_], 1);
        ebuf[pos] = ((unsigned)(d4.x & 63) << 17) | (unsigned)s4.x;
        b_ = d4.y >> 6; pos = lbase[b_] + atomicAdd(&lcnt[b_], 1);
        ebuf[pos] = ((unsigned)(d4.y & 63) << 17) | (unsigned)s4.y;
        b_ = d4.z >> 6; pos = lbase[b_] + atomicAdd(&lcnt[b_], 1);
        ebuf[pos] = ((unsigned)(d4.z & 63) << 17) | (unsigned)s4.z;
        b_ = d4.w >> 6; pos = lbase[b_] + atomicAdd(&lcnt[b_], 1);
        ebuf[pos] = ((unsigned)(d4.w & 63) << 17) | (unsigned)s4.w;
    }
}

// ---- shared aggregation + transform body (bf16 gathers, fp32 math) ----
__device__ __forceinline__ void agg_xform(
    const float* __restrict__ xin, const unsigned* __restrict__ xbf,
    const unsigned* se2, const int* lofs,
    const float* sWl, const float* sWc, const float* sbc,
    float* __restrict__ xout, unsigned* __restrict__ xbf_out,
    int emit_bf, int b, int N, int tid) {
    int n_loc = tid >> 2;
    int q = tid & 3;
    int n = b * TILE + n_loc;
    if (n >= N) return;

    int s0 = lofs[n_loc];
    int s1 = lofs[n_loc + 1];
    int deg = s1 - s0;

    float a0 = 0.f, a1 = 0.f, a2 = 0.f, a3 = 0.f;
    float c0 = 0.f, c1 = 0.f, c2 = 0.f, c3 = 0.f;
    int i = s0;
    for (; i + 8 <= s1; i += 8) {               // 8 independent 8B gathers in flight
        uint2 g[8];
        #pragma unroll
        for (int j = 0; j < 8; j++) {
            unsigned p = se2[i + j] & 0x1FFFF;
            g[j] = *(const uint2*)(xbf + (size_t)p * 8 + q * 2);
        }
        #pragma unroll
        for (int j = 0; j < 8; j += 2) {
            a0 += BLO(g[j].x); a1 += BHI(g[j].x); a2 += BLO(g[j].y); a3 += BHI(g[j].y);
            c0 += BLO(g[j + 1].x); c1 += BHI(g[j + 1].x); c2 += BLO(g[j + 1].y); c3 += BHI(g[j + 1].y);
        }
    }
    for (; i < s1; i++) {
        unsigned p = se2[i] & 0x1FFFF;
        uint2 g = *(const uint2*)(xbf + (size_t)p * 8 + q * 2);
        a0 += BLO(g.x); a1 += BHI(g.x); a2 += BLO(g.y); a3 += BHI(g.y);
    }
    a0 += c0; a1 += c1; a2 += c2; a3 += c3;

    float inv = 1.0f / fmaxf((float)deg, 1.0f);
    float a[4] = { a0 * inv, a1 * inv, a2 * inv, a3 * inv };
    float4 xq = *(const float4*)(xin + (size_t)n * D + q * 4);
    float xv[4] = { xq.x, xq.y, xq.z, xq.w };

    float o[4];
    #pragma unroll
    for (int j = 0; j < D; j++) {
        float p = 0.f;
        #pragma unroll
        for (int k = 0; k < 4; k++) {
            int kk = q * 4 + k;
            p += a[k] * sWl[j * D + kk] + xv[k] * sWc[j * D + kk];
        }
        p += __shfl_xor(p, 1, 4);
        p += __shfl_xor(p, 2, 4);
        if ((j >> 2) == q) o[j & 3] = p + sbc[j];
    }
    *(float4*)(xout + (size_t)n * D + q * 4) = make_float4(o[0], o[1], o[2], o[3]);
    if (emit_bf) {
        uint2 ob; ob.x = packbf(o[0], o[1]); ob.y = packbf(o[2], o[3]);
        *(uint2*)(xbf_out + (size_t)n * 8 + q * 2) = ob;
    }
}

// ---- layer 1: LDS counting sort (emit node_start + sorted write-back) + agg/transform ----
__global__ void layer0_kernel(const float* __restrict__ xin, const unsigned* __restrict__ xbf,
                              unsigned* __restrict__ ebuf, const int* __restrict__ cnt,
                              int* __restrict__ node_start,
                              const float* __restrict__ Wl, const float* __restrict__ bl,
                              const float* __restrict__ Wr, const float* __restrict__ Wlin,
                              const float* __restrict__ blin,
                              float* __restrict__ xout, unsigned* __restrict__ xbf_out, int N) {
    __shared__ unsigned se[CAP];
    __shared__ unsigned se2[CAP];
    __shared__ int lcnt[TILE];
    __shared__ int lofs[TILE + 1];
    __shared__ float sWl[D * D];
    __shared__ float sWc[D * D];
    __shared__ float sbc[D];

    int tid = threadIdx.x;
    int b = blockIdx.x;
    int base = b * CAP;
    int nE = min(cnt[b], CAP);

    if (tid < D * D) { sWl[tid] = Wl[tid]; sWc[tid] = Wr[tid] + Wlin[tid]; }
    if (tid < D) sbc[tid] = bl[tid] + blin[tid];
    if (tid < TILE) lcnt[tid] = 0;
    __syncthreads();
    for (int i = tid; i < nE; i += 256) {
        unsigned p = ebuf[base + i];
        se[i] = p;
        atomicAdd(&lcnt[p >> 17], 1);
    }
    __syncthreads();
    if (tid < TILE) {                // wave 0: inclusive shfl scan over 64 counters
        int v = lcnt[tid];
        int s = v;
        #pragma unroll
        for (int d_ = 1; d_ < TILE; d_ <<= 1) {
            int t = __shfl_up(s, d_, TILE);
            if (tid >= d_) s += t;
        }
        int excl = s - v;
        lofs[tid] = excl;
        lcnt[tid] = excl;            // running cursor for reorder
        node_start[b * TILE + tid] = excl;   // bucket-relative
        if (tid == TILE - 1) lofs[TILE] = s; // == nE
    }
    __syncthreads();
    for (int i = tid; i < nE; i += 256) {
        unsigned p = se[i];
        int pos = atomicAdd(&lcnt[p >> 17], 1);
        se2[pos] = p;
    }
    __syncthreads();
    for (int i = tid; i < nE; i += 256)      // coalesced sorted write-back for layers 2/3
        ebuf[base + i] = se2[i];

    agg_xform(xin, xbf, se2, lofs, sWl, sWc, sbc, xout, xbf_out, 1, b, N, tid);
}

// ---- layers 2/3: stage sorted edges, agg/transform (low LDS -> high occupancy) ----
__global__ void layerN_kernel(const float* __restrict__ xin, const unsigned* __restrict__ xbf,
                              const unsigned* __restrict__ ebuf, const int* __restrict__ cnt,
                              const int* __restrict__ node_start,
                              const float* __restrict__ Wl, const float* __restrict__ bl,
                              const float* __restrict__ Wr, const float* __restrict__ Wlin,
                              const float* __restrict__ blin,
                              float* __restrict__ xout, unsigned* __restrict__ xbf_out,
                              int emit_bf, int N) {
    __shared__ unsigned se2[CAP];
    __shared__ int lofs[TILE + 1];
    __shared__ float sWl[D * D];
    __shared__ float sWc[D * D];
    __shared__ float sbc[D];

    int tid = threadIdx.x;
    int b = blockIdx.x;
    int base = b * CAP;
    int nE = min(cnt[b], CAP);

    if (tid < D * D) { sWl[tid] = Wl[tid]; sWc[tid] = Wr[tid] + Wlin[tid]; }
    if (tid < D) sbc[tid] = bl[tid] + blin[tid];
    if (tid < TILE) lofs[tid] = node_start[b * TILE + tid];
    if (tid == 0) lofs[TILE] = nE;
    for (int i = tid; i < nE; i += 256) se2[i] = ebuf[base + i];
    __syncthreads();

    agg_xform(xin, xbf, se2, lofs, sWl, sWc, sbc, xout, xbf_out, emit_bf, b, N, tid);
}

extern "C" void kernel_launch(void* const* d_in, const int* in_sizes, int n_in,
                              void* d_out, int out_size, void* d_ws, size_t ws_size,
                              hipStream_t stream) {
    const float* x    = (const float*)d_in[0];
    const int*   ei   = (const int*)d_in[1];   // (2, E): first E = src, next E = dst
    const float* Wl   = (const float*)d_in[2];
    const float* bl   = (const float*)d_in[3];
    const float* Wr   = (const float*)d_in[4];
    const float* Wlin = (const float*)d_in[5];
    const float* blin = (const float*)d_in[6];
    float* out = (float*)d_out;

    const int* src = ei;
    const int* dst = ei + N_EDGES;

    char* w = (char*)d_ws;
    unsigned* ebuf   = (unsigned*)w;  w += (size_t)NB * CAP * 4;        // 19.2 MB
    float* bufA      = (float*)w;     w += (size_t)N_NODES * D * 4;     // 6.4 MB
    float* bufB      = (float*)w;     w += (size_t)N_NODES * D * 4;     // 6.4 MB
    unsigned* xbf0   = (unsigned*)w;  w += (size_t)N_NODES * 8 * 4;     // 3.2 MB
    unsigned* xbf1   = (unsigned*)w;  w += (size_t)N_NODES * 8 * 4;     // 3.2 MB
    int*   cursor    = (int*)w;       w += (size_t)NB * 4;
    int*   node_start= (int*)w;       w += (size_t)NB * TILE * 4;       // 400 KB

    hipMemsetAsync(cursor, 0, (size_t)NB * 4, stream);
    cvt_kernel<<<(N_NODES * D / 4 + 255) / 256, 256, 0, stream>>>(x, xbf0, N_NODES * D / 4);
    bin_scatter<<<NBLK, BINT, 0, stream>>>(src, dst, cursor, ebuf, N_EDGES);

    layer0_kernel<<<NB, 256, 0, stream>>>(
        x, xbf0, ebuf, cursor, node_start,
        Wl, bl, Wr, Wlin, blin, bufA, xbf1, N_NODES);
    layerN_kernel<<<NB, 256, 0, stream>>>(
        bufA, xbf1, ebuf, cursor, node_start,
        Wl + D * D, bl + D, Wr + D * D, Wlin + D * D, blin + D, bufB, xbf0, 1, N_NODES);
    layerN_kernel<<<NB, 256, 0, stream>>>(
        bufB, xbf0, ebuf, cursor, node_start,
        Wl + 2 * D * D, bl + 2 * D, Wr + 2 * D * D, Wlin + 2 * D * D, blin + 2 * D,
        out, xbf1, 0, N_NODES);
}

// Round 8
// 215.793 us; speedup vs baseline: 5.3250x; 1.0063x over previous
//
#include <hip/hip_runtime.h>

#define N_NODES 100000
#define N_EDGES 3200000
#define D 16
#define L 3

#define TILE 128                           // dst nodes per bucket
#define NB ((N_NODES + TILE - 1) / TILE)   // 782 buckets
#define CAP 4608                           // per-bucket ebuf region (mean 4096, +8 sigma)
#define NBLK 500                           // blocks for scatter pass
#define SEG (N_EDGES / NBLK)               // 6400 edges per block (multiple of 4)
#define BINT 1024                          // threads for scatter pass
#define LT 512                             // threads for layer kernels (TILE groups of 4)

// ---- bf16 helpers (RNE) ----
__device__ __forceinline__ unsigned packbf(float a, float b) {
    unsigned ua = __float_as_uint(a); ua += 0x7FFFu + ((ua >> 16) & 1u);
    unsigned ub = __float_as_uint(b); ub += 0x7FFFu + ((ub >> 16) & 1u);
    return (ua >> 16) | (ub & 0xFFFF0000u);
}
#define BLO(u) __uint_as_float((u) << 16)
#define BHI(u) __uint_as_float((u) & 0xFFFF0000u)

// x (fp32) -> xbf mirror (bf16 rows of 32B); t indexes float4 quarters
__global__ void cvt_kernel(const float* __restrict__ x, unsigned* __restrict__ xbf, int n4) {
    int t = blockIdx.x * blockDim.x + threadIdx.x;
    if (t >= n4) return;
    float4 v = *(const float4*)(x + (size_t)t * 4);
    uint2 o; o.x = packbf(v.x, v.y); o.y = packbf(v.z, v.w);
    *(uint2*)(xbf + (size_t)t * 2) = o;
}

// ---- single-pass scatter: LDS per-block histogram, direct global reservation ----
// packed entry: (dst & 127) << 17 | src   (src < 2^17)
__global__ void bin_scatter(const int* __restrict__ src, const int* __restrict__ dst,
                            int* __restrict__ cursor, unsigned* __restrict__ ebuf, int E) {
    __shared__ int lcnt[NB];
    __shared__ int lbase[NB];
    for (int i = threadIdx.x; i < NB; i += BINT) lcnt[i] = 0;
    __syncthreads();
    int b0 = blockIdx.x * SEG, b1 = min(E, b0 + SEG);
    for (int e = b0 + threadIdx.x * 4; e < b1; e += BINT * 4) {
        int4 d4 = *(const int4*)(dst + e);
        atomicAdd(&lcnt[d4.x >> 7], 1);
        atomicAdd(&lcnt[d4.y >> 7], 1);
        atomicAdd(&lcnt[d4.z >> 7], 1);
        atomicAdd(&lcnt[d4.w >> 7], 1);
    }
    __syncthreads();
    for (int i = threadIdx.x; i < NB; i += BINT) {
        int v = lcnt[i];
        lbase[i] = v ? (i * CAP + atomicAdd(&cursor[i], v)) : 0;
    }
    __syncthreads();
    for (int i = threadIdx.x; i < NB; i += BINT) lcnt[i] = 0;  // reuse as local cursor
    __syncthreads();
    for (int e = b0 + threadIdx.x * 4; e < b1; e += BINT * 4) {
        int4 d4 = *(const int4*)(dst + e);
        int4 s4 = *(const int4*)(src + e);
        int b_, pos;
        b_ = d4.x >> 7; pos = lbase[b_] + atomicAdd(&lcnt[b_], 1);
        ebuf[pos] = ((unsigned)(d4.x & 127) << 17) | (unsigned)s4.x;
        b_ = d4.y >> 7; pos = lbase[b_] + atomicAdd(&lcnt[b_], 1);
        ebuf[pos] = ((unsigned)(d4.y & 127) << 17) | (unsigned)s4.y;
        b_ = d4.z >> 7; pos = lbase[b_] + atomicAdd(&lcnt[b_], 1);
        ebuf[pos] = ((unsigned)(d4.z & 127) << 17) | (unsigned)s4.z;
        b_ = d4.w >> 7; pos = lbase[b_] + atomicAdd(&lcnt[b_], 1);
        ebuf[pos] = ((unsigned)(d4.w & 127) << 17) | (unsigned)s4.w;
    }
}

// ---- shared aggregation + transform body (bf16 gathers, fp32 math) ----
// n_loc comes from the degree-ranked permutation so waves are load-balanced.
__device__ __forceinline__ void agg_xform(
    const float* __restrict__ xin, const unsigned* __restrict__ xbf,
    const unsigned* se2, const int* lofs, int n_loc,
    const float* sWl, const float* sWc, const float* sbc,
    float* __restrict__ xout, unsigned* __restrict__ xbf_out,
    int emit_bf, int b, int N, int q) {
    int n = b * TILE + n_loc;
    if (n >= N) return;

    int s0 = lofs[n_loc];
    int s1 = lofs[n_loc + 1];
    int deg = s1 - s0;

    float a0 = 0.f, a1 = 0.f, a2 = 0.f, a3 = 0.f;
    float c0 = 0.f, c1 = 0.f, c2 = 0.f, c3 = 0.f;
    int i = s0;
    for (; i + 8 <= s1; i += 8) {               // 8 independent 8B gathers in flight
        uint2 g[8];
        #pragma unroll
        for (int j = 0; j < 8; j++) {
            unsigned p = se2[i + j] & 0x1FFFF;
            g[j] = *(const uint2*)(xbf + (size_t)p * 8 + q * 2);
        }
        #pragma unroll
        for (int j = 0; j < 8; j += 2) {
            a0 += BLO(g[j].x); a1 += BHI(g[j].x); a2 += BLO(g[j].y); a3 += BHI(g[j].y);
            c0 += BLO(g[j + 1].x); c1 += BHI(g[j + 1].x); c2 += BLO(g[j + 1].y); c3 += BHI(g[j + 1].y);
        }
    }
    for (; i < s1; i++) {
        unsigned p = se2[i] & 0x1FFFF;
        uint2 g = *(const uint2*)(xbf + (size_t)p * 8 + q * 2);
        a0 += BLO(g.x); a1 += BHI(g.x); a2 += BLO(g.y); a3 += BHI(g.y);
    }
    a0 += c0; a1 += c1; a2 += c2; a3 += c3;

    float inv = 1.0f / fmaxf((float)deg, 1.0f);
    float a[4] = { a0 * inv, a1 * inv, a2 * inv, a3 * inv };
    float4 xq = *(const float4*)(xin + (size_t)n * D + q * 4);
    float xv[4] = { xq.x, xq.y, xq.z, xq.w };

    float o[4];
    #pragma unroll
    for (int j = 0; j < D; j++) {
        float p = 0.f;
        #pragma unroll
        for (int k = 0; k < 4; k++) {
            int kk = q * 4 + k;
            p += a[k] * sWl[j * D + kk] + xv[k] * sWc[j * D + kk];
        }
        p += __shfl_xor(p, 1, 4);
        p += __shfl_xor(p, 2, 4);
        if ((j >> 2) == q) o[j & 3] = p + sbc[j];
    }
    *(float4*)(xout + (size_t)n * D + q * 4) = make_float4(o[0], o[1], o[2], o[3]);
    if (emit_bf) {
        uint2 ob; ob.x = packbf(o[0], o[1]); ob.y = packbf(o[2], o[3]);
        *(uint2*)(xbf_out + (size_t)n * 8 + q * 2) = ob;
    }
}

// ---- layer 1: LDS counting sort + degree rank + agg/transform ----
__global__ void layer0_kernel(const float* __restrict__ xin, const unsigned* __restrict__ xbf,
                              unsigned* __restrict__ ebuf, const int* __restrict__ cnt,
                              int* __restrict__ node_start, int* __restrict__ gperm,
                              const float* __restrict__ Wl, const float* __restrict__ bl,
                              const float* __restrict__ Wr, const float* __restrict__ Wlin,
                              const float* __restrict__ blin,
                              float* __restrict__ xout, unsigned* __restrict__ xbf_out, int N) {
    __shared__ unsigned se[CAP];
    __shared__ unsigned se2[CAP];
    __shared__ int lcnt[TILE];
    __shared__ int sscan[TILE];
    __shared__ int lofs[TILE + 1];
    __shared__ int sdeg[TILE];
    __shared__ int perm[TILE];
    __shared__ float sWl[D * D];
    __shared__ float sWc[D * D];
    __shared__ float sbc[D];

    int tid = threadIdx.x;
    int b = blockIdx.x;
    int base = b * CAP;
    int nE = min(cnt[b], CAP);

    if (tid < D * D) { sWl[tid] = Wl[tid]; sWc[tid] = Wr[tid] + Wlin[tid]; }
    if (tid < D) sbc[tid] = bl[tid] + blin[tid];
    if (tid < TILE) lcnt[tid] = 0;
    __syncthreads();
    for (int i = tid; i < nE; i += LT) {
        unsigned p = ebuf[base + i];
        se[i] = p;
        atomicAdd(&lcnt[p >> 17], 1);
    }
    __syncthreads();
    // inclusive Hillis-Steele scan over TILE counters
    if (tid < TILE) sscan[tid] = lcnt[tid];
    __syncthreads();
    for (int off = 1; off < TILE; off <<= 1) {
        int t = (tid < TILE && tid >= off) ? sscan[tid - off] : 0;
        __syncthreads();
        if (tid < TILE) sscan[tid] += t;
        __syncthreads();
    }
    if (tid < TILE) {
        int excl = sscan[tid] - lcnt[tid];
        lofs[tid] = excl;
        lcnt[tid] = excl;                    // running cursor for reorder
        sdeg[tid] = sscan[tid] - excl;       // degree
        node_start[b * TILE + tid] = excl;   // bucket-relative
        if (tid == TILE - 1) lofs[TILE] = sscan[tid];  // == nE
    }
    __syncthreads();
    // degree rank (desc): O(TILE^2) broadcast compares
    if (tid < TILE) {
        int dm = sdeg[tid];
        int r = 0;
        for (int j = 0; j < TILE; j++) {
            int dj = sdeg[j];
            r += (dj > dm) || (dj == dm && j < tid);
        }
        perm[r] = tid;
        gperm[b * TILE + r] = tid;
    }
    // reorder edges into sorted se2
    for (int i = tid; i < nE; i += LT) {
        unsigned p = se[i];
        int pos = atomicAdd(&lcnt[p >> 17], 1);
        se2[pos] = p;
    }
    __syncthreads();
    for (int i = tid; i < nE; i += LT)       // coalesced sorted write-back for layers 2/3
        ebuf[base + i] = se2[i];

    agg_xform(xin, xbf, se2, lofs, perm[tid >> 2], sWl, sWc, sbc,
              xout, xbf_out, 1, b, N, tid & 3);
}

// ---- layers 2/3: stage sorted edges, agg/transform ----
__global__ void layerN_kernel(const float* __restrict__ xin, const unsigned* __restrict__ xbf,
                              const unsigned* __restrict__ ebuf, const int* __restrict__ cnt,
                              const int* __restrict__ node_start, const int* __restrict__ gperm,
                              const float* __restrict__ Wl, const float* __restrict__ bl,
                              const float* __restrict__ Wr, const float* __restrict__ Wlin,
                              const float* __restrict__ blin,
                              float* __restrict__ xout, unsigned* __restrict__ xbf_out,
                              int emit_bf, int N) {
    __shared__ unsigned se2[CAP];
    __shared__ int lofs[TILE + 1];
    __shared__ float sWl[D * D];
    __shared__ float sWc[D * D];
    __shared__ float sbc[D];

    int tid = threadIdx.x;
    int b = blockIdx.x;
    int base = b * CAP;
    int nE = min(cnt[b], CAP);

    if (tid < D * D) { sWl[tid] = Wl[tid]; sWc[tid] = Wr[tid] + Wlin[tid]; }
    if (tid < D) sbc[tid] = bl[tid] + blin[tid];
    if (tid < TILE) lofs[tid] = node_start[b * TILE + tid];
    if (tid == 0) lofs[TILE] = nE;
    for (int i = tid; i < nE; i += LT) se2[i] = ebuf[base + i];
    int n_loc = gperm[b * TILE + (tid >> 2)];
    __syncthreads();

    agg_xform(xin, xbf, se2, lofs, n_loc, sWl, sWc, sbc,
              xout, xbf_out, emit_bf, b, N, tid & 3);
}

extern "C" void kernel_launch(void* const* d_in, const int* in_sizes, int n_in,
                              void* d_out, int out_size, void* d_ws, size_t ws_size,
                              hipStream_t stream) {
    const float* x    = (const float*)d_in[0];
    const int*   ei   = (const int*)d_in[1];   // (2, E): first E = src, next E = dst
    const float* Wl   = (const float*)d_in[2];
    const float* bl   = (const float*)d_in[3];
    const float* Wr   = (const float*)d_in[4];
    const float* Wlin = (const float*)d_in[5];
    const float* blin = (const float*)d_in[6];
    float* out = (float*)d_out;

    const int* src = ei;
    const int* dst = ei + N_EDGES;

    char* w = (char*)d_ws;
    unsigned* ebuf   = (unsigned*)w;  w += (size_t)NB * CAP * 4;        // 14.4 MB
    float* bufA      = (float*)w;     w += (size_t)N_NODES * D * 4;     // 6.4 MB
    float* bufB      = (float*)w;     w += (size_t)N_NODES * D * 4;     // 6.4 MB
    unsigned* xbf0   = (unsigned*)w;  w += (size_t)N_NODES * 8 * 4;     // 3.2 MB
    unsigned* xbf1   = (unsigned*)w;  w += (size_t)N_NODES * 8 * 4;     // 3.2 MB
    int*   cursor    = (int*)w;       w += (size_t)NB * 4;
    int*   node_start= (int*)w;       w += (size_t)NB * TILE * 4;       // 400 KB
    int*   gperm     = (int*)w;       w += (size_t)NB * TILE * 4;       // 400 KB

    hipMemsetAsync(cursor, 0, (size_t)NB * 4, stream);
    cvt_kernel<<<(N_NODES * D / 4 + 255) / 256, 256, 0, stream>>>(x, xbf0, N_NODES * D / 4);
    bin_scatter<<<NBLK, BINT, 0, stream>>>(src, dst, cursor, ebuf, N_EDGES);

    layer0_kernel<<<NB, LT, 0, stream>>>(
        x, xbf0, ebuf, cursor, node_start, gperm,
        Wl, bl, Wr, Wlin, blin, bufA, xbf1, N_NODES);
    layerN_kernel<<<NB, LT, 0, stream>>>(
        bufA, xbf1, ebuf, cursor, node_start, gperm,
        Wl + D * D, bl + D, Wr + D * D, Wlin + D * D, blin + D, bufB, xbf0, 1, N_NODES);
    layerN_kernel<<<NB, LT, 0, stream>>>(
        bufB, xbf0, ebuf, cursor, node_start, gperm,
        Wl + 2 * D * D, bl + 2 * D, Wr + 2 * D * D, Wlin + 2 * D * D, blin + 2 * D,
        out, xbf1, 0, N_NODES);
}

// Round 9
// 209.474 us; speedup vs baseline: 5.4856x; 1.0302x over previous
//
#include <hip/hip_runtime.h>

#define N_NODES 100000
#define N_EDGES 3200000
#define D 16
#define L 3

#define TILE 128                           // dst nodes per bucket
#define NB ((N_NODES + TILE - 1) / TILE)   // 782 buckets
#define CAP 4608                           // per-bucket ebuf region (mean 4096, +8 sigma)
#define NBLK 500                           // blocks for scatter pass
#define SEG (N_EDGES / NBLK)               // 6400 edges per block (multiple of 4)
#define BINT 1024                          // threads for scatter pass
#define LT 512                             // threads for layer kernels (TILE groups of 4)

// ---- bf16 helpers (RNE) ----
__device__ __forceinline__ unsigned packbf(float a, float b) {
    unsigned ua = __float_as_uint(a); ua += 0x7FFFu + ((ua >> 16) & 1u);
    unsigned ub = __float_as_uint(b); ub += 0x7FFFu + ((ub >> 16) & 1u);
    return (ua >> 16) | (ub & 0xFFFF0000u);
}
#define BLO(u) __uint_as_float((u) << 16)
#define BHI(u) __uint_as_float((u) & 0xFFFF0000u)

// x (fp32) -> xbf mirror (bf16 rows of 32B); t indexes float4 quarters
__global__ void cvt_kernel(const float* __restrict__ x, unsigned* __restrict__ xbf, int n4) {
    int t = blockIdx.x * blockDim.x + threadIdx.x;
    if (t >= n4) return;
    float4 v = *(const float4*)(x + (size_t)t * 4);
    uint2 o; o.x = packbf(v.x, v.y); o.y = packbf(v.z, v.w);
    *(uint2*)(xbf + (size_t)t * 2) = o;
}

// ---- single-pass scatter: LDS per-block histogram, direct global reservation ----
// packed entry: (dst & 127) << 17 | src   (src < 2^17)
__global__ void bin_scatter(const int* __restrict__ src, const int* __restrict__ dst,
                            int* __restrict__ cursor, unsigned* __restrict__ ebuf, int E) {
    __shared__ int lcnt[NB];
    __shared__ int lbase[NB];
    for (int i = threadIdx.x; i < NB; i += BINT) lcnt[i] = 0;
    __syncthreads();
    int b0 = blockIdx.x * SEG, b1 = min(E, b0 + SEG);
    for (int e = b0 + threadIdx.x * 4; e < b1; e += BINT * 4) {
        int4 d4 = *(const int4*)(dst + e);
        atomicAdd(&lcnt[d4.x >> 7], 1);
        atomicAdd(&lcnt[d4.y >> 7], 1);
        atomicAdd(&lcnt[d4.z >> 7], 1);
        atomicAdd(&lcnt[d4.w >> 7], 1);
    }
    __syncthreads();
    for (int i = threadIdx.x; i < NB; i += BINT) {
        int v = lcnt[i];
        lbase[i] = v ? (i * CAP + atomicAdd(&cursor[i], v)) : 0;
    }
    __syncthreads();
    for (int i = threadIdx.x; i < NB; i += BINT) lcnt[i] = 0;  // reuse as local cursor
    __syncthreads();
    for (int e = b0 + threadIdx.x * 4; e < b1; e += BINT * 4) {
        int4 d4 = *(const int4*)(dst + e);
        int4 s4 = *(const int4*)(src + e);
        int b_, pos;
        b_ = d4.x >> 7; pos = lbase[b_] + atomicAdd(&lcnt[b_], 1);
        ebuf[pos] = ((unsigned)(d4.x & 127) << 17) | (unsigned)s4.x;
        b_ = d4.y >> 7; pos = lbase[b_] + atomicAdd(&lcnt[b_], 1);
        ebuf[pos] = ((unsigned)(d4.y & 127) << 17) | (unsigned)s4.y;
        b_ = d4.z >> 7; pos = lbase[b_] + atomicAdd(&lcnt[b_], 1);
        ebuf[pos] = ((unsigned)(d4.z & 127) << 17) | (unsigned)s4.z;
        b_ = d4.w >> 7; pos = lbase[b_] + atomicAdd(&lcnt[b_], 1);
        ebuf[pos] = ((unsigned)(d4.w & 127) << 17) | (unsigned)s4.w;
    }
}

// ---- shared aggregation + transform body ----
// 4-lane group per node. Gather phase: 2 lanes per edge, 16B dwordx4 loads
// (lane q: edge parity = q>>1, row half = q&1). Post-loop shuffles move the
// half-row sums into the quarter layout the 16x16 transform uses.
__device__ __forceinline__ void agg_xform(
    const float* __restrict__ xin, const unsigned* __restrict__ xbf,
    const unsigned* se2, const int* lofs, int n_loc,
    const float* sWl, const float* sWc, const float* sbc,
    float* __restrict__ xout, unsigned* __restrict__ xbf_out,
    int emit_bf, int b, int N, int tid) {
    int q = tid & 3;
    int n = b * TILE + n_loc;
    if (n >= N) return;

    int s0 = lofs[n_loc];
    int s1 = lofs[n_loc + 1];
    int deg = s1 - s0;

    int lane2 = q >> 1;          // edge parity this lane covers
    int ho = (q & 1) * 4;        // uint offset of row half (16B)

    float acc[8] = {0.f,0.f,0.f,0.f,0.f,0.f,0.f,0.f};
    float bcc[8] = {0.f,0.f,0.f,0.f,0.f,0.f,0.f,0.f};
    int i = s0;
    for (; i + 8 <= s1; i += 8) {            // 4 independent 16B gathers in flight
        unsigned p0 = se2[i + 0 + lane2] & 0x1FFFF;
        unsigned p1 = se2[i + 2 + lane2] & 0x1FFFF;
        unsigned p2 = se2[i + 4 + lane2] & 0x1FFFF;
        unsigned p3 = se2[i + 6 + lane2] & 0x1FFFF;
        uint4 g0 = *(const uint4*)(xbf + (size_t)p0 * 8 + ho);
        uint4 g1 = *(const uint4*)(xbf + (size_t)p1 * 8 + ho);
        uint4 g2 = *(const uint4*)(xbf + (size_t)p2 * 8 + ho);
        uint4 g3 = *(const uint4*)(xbf + (size_t)p3 * 8 + ho);
        acc[0] += BLO(g0.x); acc[1] += BHI(g0.x); acc[2] += BLO(g0.y); acc[3] += BHI(g0.y);
        acc[4] += BLO(g0.z); acc[5] += BHI(g0.z); acc[6] += BLO(g0.w); acc[7] += BHI(g0.w);
        bcc[0] += BLO(g1.x); bcc[1] += BHI(g1.x); bcc[2] += BLO(g1.y); bcc[3] += BHI(g1.y);
        bcc[4] += BLO(g1.z); bcc[5] += BHI(g1.z); bcc[6] += BLO(g1.w); bcc[7] += BHI(g1.w);
        acc[0] += BLO(g2.x); acc[1] += BHI(g2.x); acc[2] += BLO(g2.y); acc[3] += BHI(g2.y);
        acc[4] += BLO(g2.z); acc[5] += BHI(g2.z); acc[6] += BLO(g2.w); acc[7] += BHI(g2.w);
        bcc[0] += BLO(g3.x); bcc[1] += BHI(g3.x); bcc[2] += BLO(g3.y); bcc[3] += BHI(g3.y);
        bcc[4] += BLO(g3.z); bcc[5] += BHI(g3.z); bcc[6] += BLO(g3.w); bcc[7] += BHI(g3.w);
    }
    for (; i + 2 <= s1; i += 2) {
        unsigned p = se2[i + lane2] & 0x1FFFF;
        uint4 g = *(const uint4*)(xbf + (size_t)p * 8 + ho);
        acc[0] += BLO(g.x); acc[1] += BHI(g.x); acc[2] += BLO(g.y); acc[3] += BHI(g.y);
        acc[4] += BLO(g.z); acc[5] += BHI(g.z); acc[6] += BLO(g.w); acc[7] += BHI(g.w);
    }
    if (i < s1 && lane2 == 0) {              // odd leftover edge: lanes q=0,1 only
        unsigned p = se2[i] & 0x1FFFF;
        uint4 g = *(const uint4*)(xbf + (size_t)p * 8 + ho);
        acc[0] += BLO(g.x); acc[1] += BHI(g.x); acc[2] += BLO(g.y); acc[3] += BHI(g.y);
        acc[4] += BLO(g.z); acc[5] += BHI(g.z); acc[6] += BLO(g.w); acc[7] += BHI(g.w);
    }
    #pragma unroll
    for (int k = 0; k < 8; k++) acc[k] += bcc[k];
    #pragma unroll
    for (int k = 0; k < 8; k++) acc[k] += __shfl_xor(acc[k], 2, 4);  // combine parities

    // redistribute half-row sums -> quarter layout: lane q wants f[4q+k]
    int srcAbs = (tid & 63 & ~3) | (q >> 1);   // group lane holding the needed half
    float inv = 1.0f / fmaxf((float)deg, 1.0f);
    float a[4];
    #pragma unroll
    for (int k = 0; k < 4; k++) {
        float lo = __shfl(acc[k], srcAbs);
        float hi = __shfl(acc[4 + k], srcAbs);
        a[k] = ((q & 1) ? hi : lo) * inv;
    }

    float4 xq = *(const float4*)(xin + (size_t)n * D + q * 4);
    float xv[4] = { xq.x, xq.y, xq.z, xq.w };

    float o[4];
    #pragma unroll
    for (int j = 0; j < D; j++) {
        float p = 0.f;
        #pragma unroll
        for (int k = 0; k < 4; k++) {
            int kk = q * 4 + k;
            p += a[k] * sWl[j * D + kk] + xv[k] * sWc[j * D + kk];
        }
        p += __shfl_xor(p, 1, 4);
        p += __shfl_xor(p, 2, 4);
        if ((j >> 2) == q) o[j & 3] = p + sbc[j];
    }
    *(float4*)(xout + (size_t)n * D + q * 4) = make_float4(o[0], o[1], o[2], o[3]);
    if (emit_bf) {
        uint2 ob; ob.x = packbf(o[0], o[1]); ob.y = packbf(o[2], o[3]);
        *(uint2*)(xbf_out + (size_t)n * 8 + q * 2) = ob;
    }
}

// ---- layer 1: LDS counting sort + degree rank + agg/transform ----
__global__ void layer0_kernel(const float* __restrict__ xin, const unsigned* __restrict__ xbf,
                              unsigned* __restrict__ ebuf, const int* __restrict__ cnt,
                              int* __restrict__ node_start, int* __restrict__ gperm,
                              const float* __restrict__ Wl, const float* __restrict__ bl,
                              const float* __restrict__ Wr, const float* __restrict__ Wlin,
                              const float* __restrict__ blin,
                              float* __restrict__ xout, unsigned* __restrict__ xbf_out, int N) {
    __shared__ unsigned se[CAP];
    __shared__ unsigned se2[CAP];
    __shared__ int lcnt[TILE];
    __shared__ int sscan[TILE];
    __shared__ int lofs[TILE + 1];
    __shared__ int sdeg[TILE];
    __shared__ int perm[TILE];
    __shared__ float sWl[D * D];
    __shared__ float sWc[D * D];
    __shared__ float sbc[D];

    int tid = threadIdx.x;
    int b = blockIdx.x;
    int base = b * CAP;
    int nE = min(cnt[b], CAP);

    if (tid < D * D) { sWl[tid] = Wl[tid]; sWc[tid] = Wr[tid] + Wlin[tid]; }
    if (tid < D) sbc[tid] = bl[tid] + blin[tid];
    if (tid < TILE) lcnt[tid] = 0;
    __syncthreads();
    for (int i = tid; i < nE; i += LT) {
        unsigned p = ebuf[base + i];
        se[i] = p;
        atomicAdd(&lcnt[p >> 17], 1);
    }
    __syncthreads();
    // inclusive Hillis-Steele scan over TILE counters
    if (tid < TILE) sscan[tid] = lcnt[tid];
    __syncthreads();
    for (int off = 1; off < TILE; off <<= 1) {
        int t = (tid < TILE && tid >= off) ? sscan[tid - off] : 0;
        __syncthreads();
        if (tid < TILE) sscan[tid] += t;
        __syncthreads();
    }
    if (tid < TILE) {
        int excl = sscan[tid] - lcnt[tid];
        lofs[tid] = excl;
        lcnt[tid] = excl;                    // running cursor for reorder
        sdeg[tid] = sscan[tid] - excl;       // degree
        node_start[b * TILE + tid] = excl;   // bucket-relative
        if (tid == TILE - 1) lofs[TILE] = sscan[tid];  // == nE
    }
    __syncthreads();
    // degree rank (desc): O(TILE^2) broadcast compares
    if (tid < TILE) {
        int dm = sdeg[tid];
        int r = 0;
        for (int j = 0; j < TILE; j++) {
            int dj = sdeg[j];
            r += (dj > dm) || (dj == dm && j < tid);
        }
        perm[r] = tid;
        gperm[b * TILE + r] = tid;
    }
    // reorder edges into sorted se2
    for (int i = tid; i < nE; i += LT) {
        unsigned p = se[i];
        int pos = atomicAdd(&lcnt[p >> 17], 1);
        se2[pos] = p;
    }
    __syncthreads();
    for (int i = tid; i < nE; i += LT)       // coalesced sorted write-back for layers 2/3
        ebuf[base + i] = se2[i];

    agg_xform(xin, xbf, se2, lofs, perm[tid >> 2], sWl, sWc, sbc,
              xout, xbf_out, 1, b, N, tid);
}

// ---- layers 2/3: stage sorted edges, agg/transform ----
__global__ void layerN_kernel(const float* __restrict__ xin, const unsigned* __restrict__ xbf,
                              const unsigned* __restrict__ ebuf, const int* __restrict__ cnt,
                              const int* __restrict__ node_start, const int* __restrict__ gperm,
                              const float* __restrict__ Wl, const float* __restrict__ bl,
                              const float* __restrict__ Wr, const float* __restrict__ Wlin,
                              const float* __restrict__ blin,
                              float* __restrict__ xout, unsigned* __restrict__ xbf_out,
                              int emit_bf, int N) {
    __shared__ unsigned se2[CAP];
    __shared__ int lofs[TILE + 1];
    __shared__ float sWl[D * D];
    __shared__ float sWc[D * D];
    __shared__ float sbc[D];

    int tid = threadIdx.x;
    int b = blockIdx.x;
    int base = b * CAP;
    int nE = min(cnt[b], CAP);

    if (tid < D * D) { sWl[tid] = Wl[tid]; sWc[tid] = Wr[tid] + Wlin[tid]; }
    if (tid < D) sbc[tid] = bl[tid] + blin[tid];
    if (tid < TILE) lofs[tid] = node_start[b * TILE + tid];
    if (tid == 0) lofs[TILE] = nE;
    for (int i = tid; i < nE; i += LT) se2[i] = ebuf[base + i];
    int n_loc = gperm[b * TILE + (tid >> 2)];
    __syncthreads();

    agg_xform(xin, xbf, se2, lofs, n_loc, sWl, sWc, sbc,
              xout, xbf_out, emit_bf, b, N, tid);
}

extern "C" void kernel_launch(void* const* d_in, const int* in_sizes, int n_in,
                              void* d_out, int out_size, void* d_ws, size_t ws_size,
                              hipStream_t stream) {
    const float* x    = (const float*)d_in[0];
    const int*   ei   = (const int*)d_in[1];   // (2, E): first E = src, next E = dst
    const float* Wl   = (const float*)d_in[2];
    const float* bl   = (const float*)d_in[3];
    const float* Wr   = (const float*)d_in[4];
    const float* Wlin = (const float*)d_in[5];
    const float* blin = (const float*)d_in[6];
    float* out = (float*)d_out;

    const int* src = ei;
    const int* dst = ei + N_EDGES;

    char* w = (char*)d_ws;
    unsigned* ebuf   = (unsigned*)w;  w += (size_t)NB * CAP * 4;        // 14.4 MB
    float* bufA      = (float*)w;     w += (size_t)N_NODES * D * 4;     // 6.4 MB
    float* bufB      = (float*)w;     w += (size_t)N_NODES * D * 4;     // 6.4 MB
    unsigned* xbf0   = (unsigned*)w;  w += (size_t)N_NODES * 8 * 4;     // 3.2 MB
    unsigned* xbf1   = (unsigned*)w;  w += (size_t)N_NODES * 8 * 4;     // 3.2 MB
    int*   cursor    = (int*)w;       w += (size_t)NB * 4;
    int*   node_start= (int*)w;       w += (size_t)NB * TILE * 4;       // 400 KB
    int*   gperm     = (int*)w;       w += (size_t)NB * TILE * 4;       // 400 KB

    hipMemsetAsync(cursor, 0, (size_t)NB * 4, stream);
    cvt_kernel<<<(N_NODES * D / 4 + 255) / 256, 256, 0, stream>>>(x, xbf0, N_NODES * D / 4);
    bin_scatter<<<NBLK, BINT, 0, stream>>>(src, dst, cursor, ebuf, N_EDGES);

    layer0_kernel<<<NB, LT, 0, stream>>>(
        x, xbf0, ebuf, cursor, node_start, gperm,
        Wl, bl, Wr, Wlin, blin, bufA, xbf1, N_NODES);
    layerN_kernel<<<NB, LT, 0, stream>>>(
        bufA, xbf1, ebuf, cursor, node_start, gperm,
        Wl + D * D, bl + D, Wr + D * D, Wlin + D * D, blin + D, bufB, xbf0, 1, N_NODES);
    layerN_kernel<<<NB, LT, 0, stream>>>(
        bufB, xbf0, ebuf, cursor, node_start, gperm,
        Wl + 2 * D * D, bl + 2 * D, Wr + 2 * D * D, Wlin + 2 * D * D, blin + 2 * D,
        out, xbf1, 0, N_NODES);
}

// Round 10
// 199.473 us; speedup vs baseline: 5.7607x; 1.0501x over previous
//
#include <hip/hip_runtime.h>

#define N_NODES 100000
#define N_EDGES 3200000
#define D 16
#define L 3

#define TILE 128                           // dst nodes per bucket
#define NB ((N_NODES + TILE - 1) / TILE)   // 782 buckets
#define CAP 4608                           // per-bucket ebuf region (mean 4096, +8 sigma)
#define NBLK 500                           // blocks for scatter pass
#define SEG (N_EDGES / NBLK)               // 6400 edges per block (multiple of 4)
#define BINT 1024                          // threads for scatter pass
#define LT 512                             // threads for layer kernels (TILE groups of 4)

// ---- bf16 helpers (RNE) ----
__device__ __forceinline__ unsigned packbf(float a, float b) {
    unsigned ua = __float_as_uint(a); ua += 0x7FFFu + ((ua >> 16) & 1u);
    unsigned ub = __float_as_uint(b); ub += 0x7FFFu + ((ub >> 16) & 1u);
    return (ua >> 16) | (ub & 0xFFFF0000u);
}
#define BLO(u) __uint_as_float((u) << 16)
#define BHI(u) __uint_as_float((u) & 0xFFFF0000u)

// x (fp32) -> xbf mirror (bf16 rows of 32B); also zeros the scatter cursor.
__global__ void cvt_kernel(const float* __restrict__ x, unsigned* __restrict__ xbf,
                           int* __restrict__ cursor, int n4) {
    int t = blockIdx.x * blockDim.x + threadIdx.x;
    if (t < NB) cursor[t] = 0;
    if (t >= n4) return;
    float4 v = *(const float4*)(x + (size_t)t * 4);
    uint2 o; o.x = packbf(v.x, v.y); o.y = packbf(v.z, v.w);
    *(uint2*)(xbf + (size_t)t * 2) = o;
}

// ---- single-pass scatter with LDS bucket-sort staging -> coalesced ebuf writes ----
// packed entry: (dst & 127) << 17 | src   (src < 2^17)
__global__ void bin_scatter(const int* __restrict__ src, const int* __restrict__ dst,
                            int* __restrict__ cursor, unsigned* __restrict__ ebuf, int E) {
    __shared__ int lcnt[NB];               // histogram, then local placement cursor
    __shared__ int ldiff[NB];              // global_base - local_offset
    __shared__ int lofs[NB];               // local exclusive offsets
    __shared__ unsigned sorted[SEG];       // bucket-sorted packed entries (also scan scratch)
    __shared__ unsigned short sbkt[SEG];   // bucket id per sorted slot
    int tid = threadIdx.x;
    for (int i = tid; i < NB; i += BINT) lcnt[i] = 0;
    __syncthreads();
    int b0 = blockIdx.x * SEG, b1 = min(E, b0 + SEG);
    // phase 1: histogram
    for (int e = b0 + tid * 4; e < b1; e += BINT * 4) {
        int4 d4 = *(const int4*)(dst + e);
        atomicAdd(&lcnt[d4.x >> 7], 1);
        atomicAdd(&lcnt[d4.y >> 7], 1);
        atomicAdd(&lcnt[d4.z >> 7], 1);
        atomicAdd(&lcnt[d4.w >> 7], 1);
    }
    __syncthreads();
    // phase 2: block-wide inclusive scan (scratch = sorted[]), reserve global space
    {
        int v = (tid < NB) ? lcnt[tid] : 0;
        sorted[tid] = (unsigned)v;
        __syncthreads();
        for (int off = 1; off < BINT; off <<= 1) {
            unsigned t = (tid >= off) ? sorted[tid - off] : 0u;
            __syncthreads();
            sorted[tid] += t;
            __syncthreads();
        }
        if (tid < NB) {
            int incl = (int)sorted[tid];
            int excl = incl - v;
            lofs[tid] = excl;
            int g = v ? (tid * CAP + atomicAdd(&cursor[tid], v)) : 0;
            ldiff[tid] = g - excl;
            lcnt[tid] = excl;              // running local cursor
        }
        __syncthreads();
    }
    // phase 3: re-read edges (L2-warm), place into bucket-sorted LDS
    for (int e = b0 + tid * 4; e < b1; e += BINT * 4) {
        int4 d4 = *(const int4*)(dst + e);
        int4 s4 = *(const int4*)(src + e);
        int b_, pos;
        b_ = d4.x >> 7; pos = atomicAdd(&lcnt[b_], 1);
        sorted[pos] = ((unsigned)(d4.x & 127) << 17) | (unsigned)s4.x; sbkt[pos] = (unsigned short)b_;
        b_ = d4.y >> 7; pos = atomicAdd(&lcnt[b_], 1);
        sorted[pos] = ((unsigned)(d4.y & 127) << 17) | (unsigned)s4.y; sbkt[pos] = (unsigned short)b_;
        b_ = d4.z >> 7; pos = atomicAdd(&lcnt[b_], 1);
        sorted[pos] = ((unsigned)(d4.z & 127) << 17) | (unsigned)s4.z; sbkt[pos] = (unsigned short)b_;
        b_ = d4.w >> 7; pos = atomicAdd(&lcnt[b_], 1);
        sorted[pos] = ((unsigned)(d4.w & 127) << 17) | (unsigned)s4.w; sbkt[pos] = (unsigned short)b_;
    }
    __syncthreads();
    // phase 4: coalesced write-out (consecutive lanes -> consecutive addresses per run)
    int nLoc = b1 - b0;
    for (int i = tid; i < nLoc; i += BINT) {
        int b_ = sbkt[i];
        ebuf[ldiff[b_] + i] = sorted[i];
    }
}

// ---- shared aggregation + transform body ----
// 4-lane group per node. Gather phase: 2 lanes per edge, 16B dwordx4 loads
// (lane q: edge parity = q>>1, row half = q&1). Post-loop shuffles move the
// half-row sums into the quarter layout the 16x16 transform uses.
__device__ __forceinline__ void agg_xform(
    const float* __restrict__ xin, const unsigned* __restrict__ xbf,
    const unsigned* se2, const int* lofs, int n_loc,
    const float* sWl, const float* sWc, const float* sbc,
    float* __restrict__ xout, unsigned* __restrict__ xbf_out,
    int emit_bf, int b, int N, int tid) {
    int q = tid & 3;
    int n = b * TILE + n_loc;
    if (n >= N) return;

    int s0 = lofs[n_loc];
    int s1 = lofs[n_loc + 1];
    int deg = s1 - s0;

    int lane2 = q >> 1;          // edge parity this lane covers
    int ho = (q & 1) * 4;        // uint offset of row half (16B)

    float acc[8] = {0.f,0.f,0.f,0.f,0.f,0.f,0.f,0.f};
    float bcc[8] = {0.f,0.f,0.f,0.f,0.f,0.f,0.f,0.f};
    int i = s0;
    for (; i + 8 <= s1; i += 8) {            // 4 independent 16B gathers in flight
        unsigned p0 = se2[i + 0 + lane2] & 0x1FFFF;
        unsigned p1 = se2[i + 2 + lane2] & 0x1FFFF;
        unsigned p2 = se2[i + 4 + lane2] & 0x1FFFF;
        unsigned p3 = se2[i + 6 + lane2] & 0x1FFFF;
        uint4 g0 = *(const uint4*)(xbf + (size_t)p0 * 8 + ho);
        uint4 g1 = *(const uint4*)(xbf + (size_t)p1 * 8 + ho);
        uint4 g2 = *(const uint4*)(xbf + (size_t)p2 * 8 + ho);
        uint4 g3 = *(const uint4*)(xbf + (size_t)p3 * 8 + ho);
        acc[0] += BLO(g0.x); acc[1] += BHI(g0.x); acc[2] += BLO(g0.y); acc[3] += BHI(g0.y);
        acc[4] += BLO(g0.z); acc[5] += BHI(g0.z); acc[6] += BLO(g0.w); acc[7] += BHI(g0.w);
        bcc[0] += BLO(g1.x); bcc[1] += BHI(g1.x); bcc[2] += BLO(g1.y); bcc[3] += BHI(g1.y);
        bcc[4] += BLO(g1.z); bcc[5] += BHI(g1.z); bcc[6] += BLO(g1.w); bcc[7] += BHI(g1.w);
        acc[0] += BLO(g2.x); acc[1] += BHI(g2.x); acc[2] += BLO(g2.y); acc[3] += BHI(g2.y);
        acc[4] += BLO(g2.z); acc[5] += BHI(g2.z); acc[6] += BLO(g2.w); acc[7] += BHI(g2.w);
        bcc[0] += BLO(g3.x); bcc[1] += BHI(g3.x); bcc[2] += BLO(g3.y); bcc[3] += BHI(g3.y);
        bcc[4] += BLO(g3.z); bcc[5] += BHI(g3.z); bcc[6] += BLO(g3.w); bcc[7] += BHI(g3.w);
    }
    for (; i + 2 <= s1; i += 2) {
        unsigned p = se2[i + lane2] & 0x1FFFF;
        uint4 g = *(const uint4*)(xbf + (size_t)p * 8 + ho);
        acc[0] += BLO(g.x); acc[1] += BHI(g.x); acc[2] += BLO(g.y); acc[3] += BHI(g.y);
        acc[4] += BLO(g.z); acc[5] += BHI(g.z); acc[6] += BLO(g.w); acc[7] += BHI(g.w);
    }
    if (i < s1 && lane2 == 0) {              // odd leftover edge: lanes q=0,1 only
        unsigned p = se2[i] & 0x1FFFF;
        uint4 g = *(const uint4*)(xbf + (size_t)p * 8 + ho);
        acc[0] += BLO(g.x); acc[1] += BHI(g.x); acc[2] += BLO(g.y); acc[3] += BHI(g.y);
        acc[4] += BLO(g.z); acc[5] += BHI(g.z); acc[6] += BLO(g.w); acc[7] += BHI(g.w);
    }
    #pragma unroll
    for (int k = 0; k < 8; k++) acc[k] += bcc[k];
    #pragma unroll
    for (int k = 0; k < 8; k++) acc[k] += __shfl_xor(acc[k], 2, 4);  // combine parities

    // redistribute half-row sums -> quarter layout: lane q wants f[4q+k]
    int srcAbs = (tid & 63 & ~3) | (q >> 1);   // group lane holding the needed half
    float inv = 1.0f / fmaxf((float)deg, 1.0f);
    float a[4];
    #pragma unroll
    for (int k = 0; k < 4; k++) {
        float lo = __shfl(acc[k], srcAbs);
        float hi = __shfl(acc[4 + k], srcAbs);
        a[k] = ((q & 1) ? hi : lo) * inv;
    }

    float4 xq = *(const float4*)(xin + (size_t)n * D + q * 4);
    float xv[4] = { xq.x, xq.y, xq.z, xq.w };

    float o[4];
    #pragma unroll
    for (int j = 0; j < D; j++) {
        float p = 0.f;
        #pragma unroll
        for (int k = 0; k < 4; k++) {
            int kk = q * 4 + k;
            p += a[k] * sWl[j * D + kk] + xv[k] * sWc[j * D + kk];
        }
        p += __shfl_xor(p, 1, 4);
        p += __shfl_xor(p, 2, 4);
        if ((j >> 2) == q) o[j & 3] = p + sbc[j];
    }
    *(float4*)(xout + (size_t)n * D + q * 4) = make_float4(o[0], o[1], o[2], o[3]);
    if (emit_bf) {
        uint2 ob; ob.x = packbf(o[0], o[1]); ob.y = packbf(o[2], o[3]);
        *(uint2*)(xbf_out + (size_t)n * 8 + q * 2) = ob;
    }
}

// ---- layer 1: LDS counting sort + degree rank + agg/transform ----
__global__ void layer0_kernel(const float* __restrict__ xin, const unsigned* __restrict__ xbf,
                              unsigned* __restrict__ ebuf, const int* __restrict__ cnt,
                              int* __restrict__ node_start, int* __restrict__ gperm,
                              const float* __restrict__ Wl, const float* __restrict__ bl,
                              const float* __restrict__ Wr, const float* __restrict__ Wlin,
                              const float* __restrict__ blin,
                              float* __restrict__ xout, unsigned* __restrict__ xbf_out, int N) {
    __shared__ unsigned se[CAP];
    __shared__ unsigned se2[CAP];
    __shared__ int lcnt[TILE];
    __shared__ int sscan[TILE];
    __shared__ int lofs[TILE + 1];
    __shared__ int sdeg[TILE];
    __shared__ int perm[TILE];
    __shared__ float sWl[D * D];
    __shared__ float sWc[D * D];
    __shared__ float sbc[D];

    int tid = threadIdx.x;
    int b = blockIdx.x;
    int base = b * CAP;
    int nE = min(cnt[b], CAP);

    if (tid < D * D) { sWl[tid] = Wl[tid]; sWc[tid] = Wr[tid] + Wlin[tid]; }
    if (tid < D) sbc[tid] = bl[tid] + blin[tid];
    if (tid < TILE) lcnt[tid] = 0;
    __syncthreads();
    for (int i = tid; i < nE; i += LT) {
        unsigned p = ebuf[base + i];
        se[i] = p;
        atomicAdd(&lcnt[p >> 17], 1);
    }
    __syncthreads();
    // inclusive Hillis-Steele scan over TILE counters
    if (tid < TILE) sscan[tid] = lcnt[tid];
    __syncthreads();
    for (int off = 1; off < TILE; off <<= 1) {
        int t = (tid < TILE && tid >= off) ? sscan[tid - off] : 0;
        __syncthreads();
        if (tid < TILE) sscan[tid] += t;
        __syncthreads();
    }
    if (tid < TILE) {
        int excl = sscan[tid] - lcnt[tid];
        lofs[tid] = excl;
        lcnt[tid] = excl;                    // running cursor for reorder
        sdeg[tid] = sscan[tid] - excl;       // degree
        node_start[b * TILE + tid] = excl;   // bucket-relative
        if (tid == TILE - 1) lofs[TILE] = sscan[tid];  // == nE
    }
    __syncthreads();
    // degree rank (desc): O(TILE^2) broadcast compares
    if (tid < TILE) {
        int dm = sdeg[tid];
        int r = 0;
        for (int j = 0; j < TILE; j++) {
            int dj = sdeg[j];
            r += (dj > dm) || (dj == dm && j < tid);
        }
        perm[r] = tid;
        gperm[b * TILE + r] = tid;
    }
    // reorder edges into sorted se2
    for (int i = tid; i < nE; i += LT) {
        unsigned p = se[i];
        int pos = atomicAdd(&lcnt[p >> 17], 1);
        se2[pos] = p;
    }
    __syncthreads();
    for (int i = tid; i < nE; i += LT)       // coalesced sorted write-back for layers 2/3
        ebuf[base + i] = se2[i];

    agg_xform(xin, xbf, se2, lofs, perm[tid >> 2], sWl, sWc, sbc,
              xout, xbf_out, 1, b, N, tid);
}

// ---- layers 2/3: stage sorted edges, agg/transform ----
__global__ void layerN_kernel(const float* __restrict__ xin, const unsigned* __restrict__ xbf,
                              const unsigned* __restrict__ ebuf, const int* __restrict__ cnt,
                              const int* __restrict__ node_start, const int* __restrict__ gperm,
                              const float* __restrict__ Wl, const float* __restrict__ bl,
                              const float* __restrict__ Wr, const float* __restrict__ Wlin,
                              const float* __restrict__ blin,
                              float* __restrict__ xout, unsigned* __restrict__ xbf_out,
                              int emit_bf, int N) {
    __shared__ unsigned se2[CAP];
    __shared__ int lofs[TILE + 1];
    __shared__ float sWl[D * D];
    __shared__ float sWc[D * D];
    __shared__ float sbc[D];

    int tid = threadIdx.x;
    int b = blockIdx.x;
    int base = b * CAP;
    int nE = min(cnt[b], CAP);

    if (tid < D * D) { sWl[tid] = Wl[tid]; sWc[tid] = Wr[tid] + Wlin[tid]; }
    if (tid < D) sbc[tid] = bl[tid] + blin[tid];
    if (tid < TILE) lofs[tid] = node_start[b * TILE + tid];
    if (tid == 0) lofs[TILE] = nE;
    for (int i = tid; i < nE; i += LT) se2[i] = ebuf[base + i];
    int n_loc = gperm[b * TILE + (tid >> 2)];
    __syncthreads();

    agg_xform(xin, xbf, se2, lofs, n_loc, sWl, sWc, sbc,
              xout, xbf_out, emit_bf, b, N, tid);
}

extern "C" void kernel_launch(void* const* d_in, const int* in_sizes, int n_in,
                              void* d_out, int out_size, void* d_ws, size_t ws_size,
                              hipStream_t stream) {
    const float* x    = (const float*)d_in[0];
    const int*   ei   = (const int*)d_in[1];   // (2, E): first E = src, next E = dst
    const float* Wl   = (const float*)d_in[2];
    const float* bl   = (const float*)d_in[3];
    const float* Wr   = (const float*)d_in[4];
    const float* Wlin = (const float*)d_in[5];
    const float* blin = (const float*)d_in[6];
    float* out = (float*)d_out;

    const int* src = ei;
    const int* dst = ei + N_EDGES;

    char* w = (char*)d_ws;
    unsigned* ebuf   = (unsigned*)w;  w += (size_t)NB * CAP * 4;        // 14.4 MB
    float* bufA      = (float*)w;     w += (size_t)N_NODES * D * 4;     // 6.4 MB
    float* bufB      = (float*)w;     w += (size_t)N_NODES * D * 4;     // 6.4 MB
    unsigned* xbf0   = (unsigned*)w;  w += (size_t)N_NODES * 8 * 4;     // 3.2 MB
    unsigned* xbf1   = (unsigned*)w;  w += (size_t)N_NODES * 8 * 4;     // 3.2 MB
    int*   cursor    = (int*)w;       w += (size_t)NB * 4;
    int*   node_start= (int*)w;       w += (size_t)NB * TILE * 4;       // 400 KB
    int*   gperm     = (int*)w;       w += (size_t)NB * TILE * 4;       // 400 KB

    cvt_kernel<<<(N_NODES * D / 4 + 255) / 256, 256, 0, stream>>>(
        x, xbf0, cursor, N_NODES * D / 4);
    bin_scatter<<<NBLK, BINT, 0, stream>>>(src, dst, cursor, ebuf, N_EDGES);

    layer0_kernel<<<NB, LT, 0, stream>>>(
        x, xbf0, ebuf, cursor, node_start, gperm,
        Wl, bl, Wr, Wlin, blin, bufA, xbf1, N_NODES);
    layerN_kernel<<<NB, LT, 0, stream>>>(
        bufA, xbf1, ebuf, cursor, node_start, gperm,
        Wl + D * D, bl + D, Wr + D * D, Wlin + D * D, blin + D, bufB, xbf0, 1, N_NODES);
    layerN_kernel<<<NB, LT, 0, stream>>>(
        bufB, xbf0, ebuf, cursor, node_start, gperm,
        Wl + 2 * D * D, bl + 2 * D, Wr + 2 * D * D, Wlin + 2 * D * D, blin + 2 * D,
        out, xbf1, 0, N_NODES);
}